// Round 1
// 278.964 us; speedup vs baseline: 1.0186x; 1.0186x over previous
//
#include <hip/hip_runtime.h>
#include <math.h>

#define B_  32
#define S_  1024
#define D_  256
#define H_  8
#define DK_ 32
#define MASKV (-1e-30f)
#define LOG2E 1.44269504f

typedef __attribute__((ext_vector_type(4))) short bf4_t;   // 4 bf16 (2 VGPRs)
typedef __attribute__((ext_vector_type(8))) short bf8_t;   // 8 bf16 (4 VGPRs)
typedef __attribute__((ext_vector_type(4))) float f4_t;    // MFMA accumulator

__device__ __forceinline__ unsigned fbits(float x) {
    union { float f; unsigned u; } v; v.f = x; return v.u;
}
__device__ __forceinline__ float bitsf(unsigned u) {
    union { unsigned u; float f; } v; v.u = u; return v.f;
}

#if __has_builtin(__builtin_amdgcn_exp2f)
#define EXP2F(x) __builtin_amdgcn_exp2f(x)
#else
#define EXP2F(x) __expf((x) * 0.69314718f)
#endif

__device__ __forceinline__ void gld16(const void* g, void* l) {
    __builtin_amdgcn_global_load_lds(
        (const __attribute__((address_space(1))) void*)g,
        (__attribute__((address_space(3))) void*)l, 16, 0, 0);
}

// v_perm selector: D = [S1.hi16 (low half), S0.hi16 (high half)]
#define PSEL 0x07060302u

// ---------------------------------------------------------------------------
// prep_w: W[h][d][k] fp32 -> Wt[(a*256)+(h*32+k)][d] hi/lo bf16.
// Coalesced reads (lanes sweep k along a 128-B line), packed uint2 stores
// (4 consecutive d per store). grid (24,4): blockIdx.y splits the d range.
// ---------------------------------------------------------------------------
__global__ __launch_bounds__(256) void prep_w(
    const float* __restrict__ Wq, const float* __restrict__ Wk,
    const float* __restrict__ Wv, short* __restrict__ WtH, short* __restrict__ WtL)
{
    const int a = blockIdx.x >> 3;
    const int h = blockIdx.x & 7;
    const float* W = (a == 0 ? Wq : (a == 1 ? Wk : Wv)) + (size_t)h * 256 * 32;
    const int t = threadIdx.x;
    const int k    = t & 31;
    const int dgrp = t >> 5;                 // 0..7
    short* th = WtH + ((size_t)a * 256 + h * 32 + k) * 256;
    short* tl = WtL + ((size_t)a * 256 + h * 32 + k) * 256;
#pragma unroll
    for (int jj = blockIdx.y * 2; jj < blockIdx.y * 2 + 2; ++jj) {
        const int d0 = jj * 32 + dgrp * 4;
        float x[4];
#pragma unroll
        for (int r = 0; r < 4; ++r) x[r] = W[(size_t)(d0 + r) * 32 + k];
        unsigned hu[4], lu[4];
#pragma unroll
        for (int r = 0; r < 4; ++r) {
            unsigned hb = (fbits(x[r]) + 0x8000u) & 0xFFFF0000u;
            hu[r] = hb;
            lu[r] = fbits(x[r] - bitsf(hb)) + 0x8000u;
        }
        uint2 hp = make_uint2(__builtin_amdgcn_perm(hu[1], hu[0], PSEL),
                              __builtin_amdgcn_perm(hu[3], hu[2], PSEL));
        uint2 lp = make_uint2(__builtin_amdgcn_perm(lu[1], lu[0], PSEL),
                              __builtin_amdgcn_perm(lu[3], lu[2], PSEL));
        *(uint2*)&th[d0] = hp;
        *(uint2*)&tl[d0] = lp;
    }
}

// ---------------------------------------------------------------------------
// proj: C[32768,256] = X * Wt^T via split-bf16 MFMA.
// a<2 (Q,K): A=W, B=X -> D[col=s][row=n_w]; Q additionally scaled by LOG2E
//            so attn can use raw exp2; K scaled by mask[b][s] (MASKV = -1e-30
//            makes reference masking equivalent to zeroing masked K rows:
//            score becomes exactly 0 -> P = exp2(0) = 1 = exp(-1e-30)).
// a==2 (V):  A=X, B=W -> D[col=n_w][row=s]; packed 8B stores to [bh][dv][s].
// W staging (async global_load_lds) is issued BEFORE the VALU-heavy X
// conversion so the loads fly under it.
// ---------------------------------------------------------------------------
__global__ __launch_bounds__(256) void proj_kernel(
    const float* __restrict__ Xq, const float* __restrict__ Xk,
    const float* __restrict__ Xv, const float* __restrict__ mask,
    const short* __restrict__ WtH, const short* __restrict__ WtL,
    short* __restrict__ qpH, short* __restrict__ qpL,
    short* __restrict__ kpH, short* __restrict__ kpL,
    short* __restrict__ vpT)
{
    __shared__ __align__(16) short XsH[64 * 32];
    __shared__ __align__(16) short XsL[64 * 32];
    __shared__ __align__(16) short WsH[256 * 32];
    __shared__ __align__(16) short WsL[256 * 32];

    const int a  = blockIdx.y;
    const float* X = (a == 0 ? Xq : (a == 1 ? Xk : Xv));
    const short* WH = WtH + (size_t)a * 256 * 256;
    const short* WL = WtL + (size_t)a * 256 * 256;
    const int m0 = blockIdx.x * 64;

    const int tid  = threadIdx.x;
    const int lane = tid & 63;
    const int wv   = tid >> 6;
    const int l15  = lane & 15;
    const int quad = lane >> 4;

    f4_t acc[4][4];
#pragma unroll
    for (int i = 0; i < 4; ++i)
#pragma unroll
        for (int j = 0; j < 4; ++j) acc[i][j] = (f4_t){0.f, 0.f, 0.f, 0.f};

    for (int kc = 0; kc < 8; ++kc) {
        __syncthreads();
        // ---- stage W via global_load_lds (async; issue first) ----
#pragma unroll
        for (int i = 0; i < 4; ++i) {
            size_t go = (size_t)((i * 4 + wv) * 16 + (lane >> 2)) * 256 + kc * 32 + (lane & 3) * 8;
            gld16(WH + go, (char*)WsH + (i * 4 + wv) * 1024);
            gld16(WL + go, (char*)WsL + (i * 4 + wv) * 1024);
        }
        // ---- stage X (fp32 -> hi/lo) while W loads fly ----
        {
            const float* xp = X + (size_t)(m0 + (tid >> 2)) * 256 + kc * 32 + (tid & 3) * 8;
            float4 x0 = *(const float4*)xp;
            float4 x1 = *(const float4*)(xp + 4);
            float xv[8] = {x0.x, x0.y, x0.z, x0.w, x1.x, x1.y, x1.z, x1.w};
            bf8_t hi, lo;
#pragma unroll
            for (int j = 0; j < 8; ++j) {
                unsigned hu = (fbits(xv[j]) + 0x8000u) & 0xFFFF0000u;
                hi[j] = (short)(hu >> 16);
                lo[j] = (short)((fbits(xv[j] - bitsf(hu)) + 0x8000u) >> 16);
            }
            *(bf8_t*)&XsH[(tid >> 2) * 32 + (tid & 3) * 8] = hi;
            *(bf8_t*)&XsL[(tid >> 2) * 32 + (tid & 3) * 8] = lo;
        }
        __syncthreads();

        bf8_t wH[4], wL[4];
#pragma unroll
        for (int ns = 0; ns < 4; ++ns) {
            int n = wv * 64 + ns * 16 + l15;
            wH[ns] = *(const bf8_t*)&WsH[n * 32 + quad * 8];
            wL[ns] = *(const bf8_t*)&WsL[n * 32 + quad * 8];
        }
#pragma unroll
        for (int t = 0; t < 4; ++t) {
            bf8_t xH = *(const bf8_t*)&XsH[(t * 16 + l15) * 32 + quad * 8];
            bf8_t xL = *(const bf8_t*)&XsL[(t * 16 + l15) * 32 + quad * 8];
#pragma unroll
            for (int ns = 0; ns < 4; ++ns) {
                f4_t c = acc[t][ns];
                if (a < 2) {
                    c = __builtin_amdgcn_mfma_f32_16x16x32_bf16(wH[ns], xH, c, 0, 0, 0);
                    c = __builtin_amdgcn_mfma_f32_16x16x32_bf16(wL[ns], xH, c, 0, 0, 0);
                    c = __builtin_amdgcn_mfma_f32_16x16x32_bf16(wH[ns], xL, c, 0, 0, 0);
                } else {
                    c = __builtin_amdgcn_mfma_f32_16x16x32_bf16(xH, wH[ns], c, 0, 0, 0);
                    c = __builtin_amdgcn_mfma_f32_16x16x32_bf16(xH, wL[ns], c, 0, 0, 0);
                    c = __builtin_amdgcn_mfma_f32_16x16x32_bf16(xL, wH[ns], c, 0, 0, 0);
                }
                acc[t][ns] = c;
            }
        }
    }

    // ---- epilogue ----
    const int b  = m0 >> 10;
    const int sB = m0 & 1023;
    if (a < 2) {
        short* dH = (a == 0) ? qpH : kpH;
        short* dL = (a == 0) ? qpL : kpL;
        const float* mbp = mask + (size_t)b * 1024;
#pragma unroll
        for (int t = 0; t < 4; ++t) {
            int s = sB + t * 16 + l15;
            // Q: fold exp2 conversion; K: fold mask (zero masked key rows)
            const float scale = (a == 0) ? LOG2E : mbp[s];
#pragma unroll
            for (int ns = 0; ns < 4; ++ns) {
                int nw = wv * 64 + ns * 16 + quad * 4;
                int h = nw >> 5, k0 = nw & 31;
                unsigned hu[4], lu[4];
#pragma unroll
                for (int r = 0; r < 4; ++r) {
                    float x = acc[t][ns][r] * scale;
                    unsigned h32 = fbits(x) + 0x8000u;
                    hu[r] = h32;
                    float hf = bitsf(h32 & 0xFFFF0000u);
                    lu[r] = fbits(x - hf) + 0x8000u;
                }
                uint2 hp = make_uint2(__builtin_amdgcn_perm(hu[1], hu[0], PSEL),
                                      __builtin_amdgcn_perm(hu[3], hu[2], PSEL));
                uint2 lp = make_uint2(__builtin_amdgcn_perm(lu[1], lu[0], PSEL),
                                      __builtin_amdgcn_perm(lu[3], lu[2], PSEL));
                size_t off = ((size_t)(b * 8 + h) * 1024 + s) * 32 + k0;
                *(uint2*)&dH[off] = hp;
                *(uint2*)&dL[off] = lp;
            }
        }
    } else {
#pragma unroll
        for (int t = 0; t < 4; ++t) {
            int sr = sB + t * 16 + quad * 4;
#pragma unroll
            for (int ns = 0; ns < 4; ++ns) {
                int n = wv * 64 + ns * 16 + l15;
                int h = n >> 5, k = n & 31;
                unsigned eu[4];
#pragma unroll
                for (int r = 0; r < 4; ++r) eu[r] = fbits(acc[t][ns][r]) + 0x8000u;
                uint2 pk = make_uint2(__builtin_amdgcn_perm(eu[1], eu[0], PSEL),
                                      __builtin_amdgcn_perm(eu[3], eu[2], PSEL));
                *(uint2*)&vpT[((size_t)(b * 8 + h) * 32 + k) * 1024 + sr] = pk;
            }
        }
    }
}

// ---------------------------------------------------------------------------
// attn: block = 128 queries (4 waves x 32 q), 16 k-tiles of 64 keys.
// Mask is pre-folded into K (masked key rows are zero -> score 0 -> P = 1,
// exactly the reference's -1e-30 semantics), so the inner loop is pure
// QK^T -> exp2 -> PV. No online max (scores bounded ~|62| << 88).
// 2-phase prefetch: double-buffered K/V LDS; tile kt+1 is staged (async
// global_load_lds for K, reg-staged deferred ds_write for V) WHILE tile kt
// computes; ONE barrier per iteration (its implicit vmcnt(0) drain lands
// after compute, hiding the staging latency -- T3 minimum-2-phase).
// XCD swizzle: each XCD owns a contiguous bh range so the 8 q-tile blocks
// sharing one head's K/V hit the same L2 (bijective: 2048 % 8 == 0).
// ---------------------------------------------------------------------------
__global__ __launch_bounds__(256) void attn_kernel(
    const short* __restrict__ qpH, const short* __restrict__ qpL,
    const short* __restrict__ kpH, const short* __restrict__ kpL,
    const short* __restrict__ vpT, float* __restrict__ out)
{
    __shared__ __align__(16) short KsH[2][64 * 32];
    __shared__ __align__(16) short KsL[2][64 * 32];
    __shared__ __align__(16) short VsT[2][32 * 72];

    const int tid  = threadIdx.x;
    const int lane = tid & 63;
    const int wv   = tid >> 6;
    const int l15  = lane & 15;
    const int quad = lane >> 4;

    // launch-linear id -> XCD-contiguous (bh, qt) assignment
    const int L  = (blockIdx.z * gridDim.y + blockIdx.y) * gridDim.x + blockIdx.x;
    const int li = L >> 3;
    const int bh = (L & 7) * 32 + (li >> 3);
    const int qt = li & 7;
    const int b  = bh >> 3;
    const int h  = bh & 7;
    const int woff = qt * 128 + wv * 32;

    bf8_t qh[2], ql[2];
#pragma unroll
    for (int qs = 0; qs < 2; ++qs) {
        size_t row = (size_t)bh * 1024 + woff + qs * 16 + l15;
        qh[qs] = *(const bf8_t*)&qpH[row * 32 + quad * 8];
        ql[qs] = *(const bf8_t*)&qpL[row * 32 + quad * 8];
    }

    f4_t accO[2][2];
    f4_t accS[2];
#pragma unroll
    for (int i = 0; i < 2; ++i) {
        accS[i] = (f4_t){0.f, 0.f, 0.f, 0.f};
#pragma unroll
        for (int j = 0; j < 2; ++j) accO[i][j] = (f4_t){0.f, 0.f, 0.f, 0.f};
    }
    const bf4_t ones4 = {(short)0x3F80, (short)0x3F80, (short)0x3F80, (short)0x3F80};

    const int dv = tid >> 3, seg = tid & 7;

    // ---- prologue: stage tile 0 -> buf 0 ----
    {
        size_t toff = ((size_t)bh * 1024) * 32;
        gld16(kpH + toff + wv * 512 + lane * 8, (char*)KsH[0] + wv * 1024);
        gld16(kpL + toff + wv * 512 + lane * 8, (char*)KsL[0] + wv * 1024);
        uint4 v0 = *(const uint4*)&vpT[((size_t)bh * 32 + dv) * 1024 + seg * 8];
        *(uint4*)&VsT[0][dv * 72 + seg * 8] = v0;
    }
    __syncthreads();

    int cur = 0;
    for (int kt = 0; kt < 16; ++kt) {
        const int nxt = cur ^ 1;

        // ---- issue staging of tile kt+1 into buf nxt (no wait here) ----
        uint4 vreg;
        if (kt < 15) {
            size_t toff = ((size_t)bh * 1024 + (kt + 1) * 64) * 32;
            gld16(kpH + toff + wv * 512 + lane * 8, (char*)KsH[nxt] + wv * 1024);
            gld16(kpL + toff + wv * 512 + lane * 8, (char*)KsL[nxt] + wv * 1024);
            vreg = *(const uint4*)&vpT[((size_t)bh * 32 + dv) * 1024 + (kt + 1) * 64 + seg * 8];
        }

        // ---- scores (Q pre-scaled by log2e) ----
        f4_t sc[2][4];
#pragma unroll
        for (int ks = 0; ks < 4; ++ks) {
            bf8_t kh = *(const bf8_t*)&KsH[cur][(ks * 16 + l15) * 32 + quad * 8];
            bf8_t kl = *(const bf8_t*)&KsL[cur][(ks * 16 + l15) * 32 + quad * 8];
#pragma unroll
            for (int qs = 0; qs < 2; ++qs) {
                f4_t c = __builtin_amdgcn_mfma_f32_16x16x32_bf16(kh, qh[qs],
                             (f4_t){0.f, 0.f, 0.f, 0.f}, 0, 0, 0);
                c = __builtin_amdgcn_mfma_f32_16x16x32_bf16(kl, qh[qs], c, 0, 0, 0);
                c = __builtin_amdgcn_mfma_f32_16x16x32_bf16(kh, ql[qs], c, 0, 0, 0);
                sc[qs][ks] = c;
            }
        }

        // ---- P = exp2(score), packed to bf16 (mask already folded into K) ----
        bf4_t pf[2][4];
#pragma unroll
        for (int ks = 0; ks < 4; ++ks) {
#pragma unroll
            for (int qs = 0; qs < 2; ++qs) {
                unsigned eu[4];
#pragma unroll
                for (int r = 0; r < 4; ++r)
                    eu[r] = fbits(EXP2F(sc[qs][ks][r])) + 0x8000u;
                union { uint2 u; bf4_t v; } cv;
                cv.u = make_uint2(__builtin_amdgcn_perm(eu[1], eu[0], PSEL),
                                  __builtin_amdgcn_perm(eu[3], eu[2], PSEL));
                pf[qs][ks] = cv.v;
            }
        }

        // ---- PV + sum ----
#pragma unroll
        for (int ks = 0; ks < 4; ++ks) {
            bf4_t vf0 = *(const bf4_t*)&VsT[cur][l15 * 72 + ks * 16 + quad * 4];
            bf4_t vf1 = *(const bf4_t*)&VsT[cur][(16 + l15) * 72 + ks * 16 + quad * 4];
#pragma unroll
            for (int qs = 0; qs < 2; ++qs) {
                accO[qs][0] = __builtin_amdgcn_mfma_f32_16x16x16bf16_1k(vf0, pf[qs][ks], accO[qs][0], 0, 0, 0);
                accO[qs][1] = __builtin_amdgcn_mfma_f32_16x16x16bf16_1k(vf1, pf[qs][ks], accO[qs][1], 0, 0, 0);
                accS[qs]    = __builtin_amdgcn_mfma_f32_16x16x16bf16_1k(ones4, pf[qs][ks], accS[qs], 0, 0, 0);
            }
        }

        // ---- deferred V write for tile kt+1 (vmcnt wait lands here) ----
        if (kt < 15) *(uint4*)&VsT[nxt][dv * 72 + seg * 8] = vreg;
        __syncthreads();
        cur = nxt;
    }

    // ---- epilogue ----
#pragma unroll
    for (int qs = 0; qs < 2; ++qs) {
        float inv = 1.0f / accS[qs][0];
        int s = woff + qs * 16 + l15;
        float* op = out + ((size_t)b * 1024 + s) * 256 + h * 32;
#pragma unroll
        for (int dvs = 0; dvs < 2; ++dvs) {
            float4 o4 = make_float4(accO[qs][dvs][0] * inv, accO[qs][dvs][1] * inv,
                                    accO[qs][dvs][2] * inv, accO[qs][dvs][3] * inv);
            *(float4*)&op[dvs * 16 + quad * 4] = o4;
        }
    }
}

// ---------------------------------------------------------------------------
extern "C" void kernel_launch(void* const* d_in, const int* in_sizes, int n_in,
                              void* d_out, int out_size, void* d_ws, size_t ws_size,
                              hipStream_t stream)
{
    const float* query = (const float*)d_in[0];
    const float* key   = (const float*)d_in[1];
    const float* value = (const float*)d_in[2];
    const float* mask  = (const float*)d_in[3];
    const float* Wq    = (const float*)d_in[4];
    const float* Wk    = (const float*)d_in[5];
    const float* Wv    = (const float*)d_in[6];
    float* out = (float*)d_out;

    const size_t per = (size_t)B_ * H_ * S_ * DK_;
    short* qpH = (short*)d_ws;
    short* qpL = qpH + per;
    short* kpH = qpL + per;
    short* kpL = kpH + per;
    short* vpT = kpL + per;
    short* WtH = vpT + per;
    short* WtL = WtH + 3 * 256 * 256;

    prep_w<<<dim3(24, 4), 256, 0, stream>>>(Wq, Wk, Wv, WtH, WtL);
    proj_kernel<<<dim3(512, 3), 256, 0, stream>>>(query, key, value, mask, WtH, WtL,
                                                  qpH, qpL, kpH, kpL, vpT);
    attn_kernel<<<dim3(8, H_, B_), 256, 0, stream>>>(qpH, qpL, kpH, kpL, vpT, out);
}

// Round 2
// 278.905 us; speedup vs baseline: 1.0189x; 1.0002x over previous
//
#include <hip/hip_runtime.h>
#include <math.h>

#define B_  32
#define S_  1024
#define D_  256
#define H_  8
#define DK_ 32
#define MASKV (-1e-30f)
#define LOG2E 1.44269504f

typedef __attribute__((ext_vector_type(4))) short bf4_t;   // 4 bf16 (2 VGPRs)
typedef __attribute__((ext_vector_type(8))) short bf8_t;   // 8 bf16 (4 VGPRs)
typedef __attribute__((ext_vector_type(4))) float f4_t;    // MFMA accumulator

__device__ __forceinline__ unsigned fbits(float x) {
    union { float f; unsigned u; } v; v.f = x; return v.u;
}
__device__ __forceinline__ float bitsf(unsigned u) {
    union { unsigned u; float f; } v; v.u = u; return v.f;
}

#if __has_builtin(__builtin_amdgcn_exp2f)
#define EXP2F(x) __builtin_amdgcn_exp2f(x)
#else
#define EXP2F(x) __expf((x) * 0.69314718f)
#endif

__device__ __forceinline__ void gld16(const void* g, void* l) {
    __builtin_amdgcn_global_load_lds(
        (const __attribute__((address_space(1))) void*)g,
        (__attribute__((address_space(3))) void*)l, 16, 0, 0);
}

// v_perm selector: D = [S1.hi16 (low half), S0.hi16 (high half)]
#define PSEL 0x07060302u

// LDS tile swizzle (T2): tiles are row-major [R][32] shorts (64 B rows).
// ds_read_b128 of a column-slice puts 16 lanes at 64 B stride -> 8 of 32
// banks -> 4x serialization. Involution: quad (byte bits 4-5) ^= row bits
// 1-2 (byte bits 7-8). Both sides (stage source pre-swizzle for
// global_load_lds linear dest; swizzled ds_write/ds_read) use the SAME xor.

// ---------------------------------------------------------------------------
// prep_w: W[h][d][k] fp32 -> Wt[(a*256)+(h*32+k)][d] hi/lo bf16.
// ---------------------------------------------------------------------------
__global__ __launch_bounds__(256) void prep_w(
    const float* __restrict__ Wq, const float* __restrict__ Wk,
    const float* __restrict__ Wv, short* __restrict__ WtH, short* __restrict__ WtL)
{
    const int a = blockIdx.x >> 3;
    const int h = blockIdx.x & 7;
    const float* W = (a == 0 ? Wq : (a == 1 ? Wk : Wv)) + (size_t)h * 256 * 32;
    const int t = threadIdx.x;
    const int k    = t & 31;
    const int dgrp = t >> 5;                 // 0..7
    short* th = WtH + ((size_t)a * 256 + h * 32 + k) * 256;
    short* tl = WtL + ((size_t)a * 256 + h * 32 + k) * 256;
#pragma unroll
    for (int jj = blockIdx.y * 2; jj < blockIdx.y * 2 + 2; ++jj) {
        const int d0 = jj * 32 + dgrp * 4;
        float x[4];
#pragma unroll
        for (int r = 0; r < 4; ++r) x[r] = W[(size_t)(d0 + r) * 32 + k];
        unsigned hu[4], lu[4];
#pragma unroll
        for (int r = 0; r < 4; ++r) {
            unsigned hb = (fbits(x[r]) + 0x8000u) & 0xFFFF0000u;
            hu[r] = hb;
            lu[r] = fbits(x[r] - bitsf(hb)) + 0x8000u;
        }
        uint2 hp = make_uint2(__builtin_amdgcn_perm(hu[1], hu[0], PSEL),
                              __builtin_amdgcn_perm(hu[3], hu[2], PSEL));
        uint2 lp = make_uint2(__builtin_amdgcn_perm(lu[1], lu[0], PSEL),
                              __builtin_amdgcn_perm(lu[3], lu[2], PSEL));
        *(uint2*)&th[d0] = hp;
        *(uint2*)&tl[d0] = lp;
    }
}

// ---------------------------------------------------------------------------
// proj: C[32768,256] = X * Wt^T via split-bf16 MFMA.
// a<2 (Q,K): A=W, B=X; Q scaled by LOG2E, K scaled by mask[b][s] (MASKV
//            ~= 0 makes reference masking == zeroing masked K rows).
// a==2 (V):  A=X, B=W; packed 8B stores to [bh][dv][s].
// LDS tiles XOR-swizzled (see above) to kill the 4x ds_read_b128 conflicts.
// ---------------------------------------------------------------------------
__global__ __launch_bounds__(256) void proj_kernel(
    const float* __restrict__ Xq, const float* __restrict__ Xk,
    const float* __restrict__ Xv, const float* __restrict__ mask,
    const short* __restrict__ WtH, const short* __restrict__ WtL,
    short* __restrict__ qpH, short* __restrict__ qpL,
    short* __restrict__ kpH, short* __restrict__ kpL,
    short* __restrict__ vpT)
{
    __shared__ __align__(16) short XsH[64 * 32];
    __shared__ __align__(16) short XsL[64 * 32];
    __shared__ __align__(16) short WsH[256 * 32];
    __shared__ __align__(16) short WsL[256 * 32];

    const int a  = blockIdx.y;
    const float* X = (a == 0 ? Xq : (a == 1 ? Xk : Xv));
    const short* WH = WtH + (size_t)a * 256 * 256;
    const short* WL = WtL + (size_t)a * 256 * 256;
    const int m0 = blockIdx.x * 64;

    const int tid  = threadIdx.x;
    const int lane = tid & 63;
    const int wv   = tid >> 6;
    const int l15  = lane & 15;
    const int quad = lane >> 4;
    // swizzled column-slice selector for fragment reads (row bits 1-2 == l15 bits 1-2)
    const int q2r  = quad ^ ((l15 >> 1) & 3);
    // swizzled source quad for gld16 staging (row bits 1-2 == lane bits 3-4)
    const int q2s  = (lane & 3) ^ ((lane >> 3) & 3);
    // swizzled store quad for X staging (row = tid>>2 -> bits 1-2 = (tid>>3)&3)
    const int q2x  = (tid & 3) ^ ((tid >> 3) & 3);

    f4_t acc[4][4];
#pragma unroll
    for (int i = 0; i < 4; ++i)
#pragma unroll
        for (int j = 0; j < 4; ++j) acc[i][j] = (f4_t){0.f, 0.f, 0.f, 0.f};

    for (int kc = 0; kc < 8; ++kc) {
        __syncthreads();
        // ---- stage W via global_load_lds (linear dest, pre-swizzled source) ----
#pragma unroll
        for (int i = 0; i < 4; ++i) {
            int row = (i * 4 + wv) * 16 + (lane >> 2);
            size_t go = (size_t)row * 256 + kc * 32 + q2s * 8;
            gld16(WH + go, (char*)WsH + (i * 4 + wv) * 1024);
            gld16(WL + go, (char*)WsL + (i * 4 + wv) * 1024);
        }
        // ---- stage X (fp32 -> hi/lo) while W loads fly; swizzled ds_write ----
        {
            const float* xp = X + (size_t)(m0 + (tid >> 2)) * 256 + kc * 32 + (tid & 3) * 8;
            float4 x0 = *(const float4*)xp;
            float4 x1 = *(const float4*)(xp + 4);
            float xv[8] = {x0.x, x0.y, x0.z, x0.w, x1.x, x1.y, x1.z, x1.w};
            bf8_t hi, lo;
#pragma unroll
            for (int j = 0; j < 8; ++j) {
                unsigned hu = (fbits(xv[j]) + 0x8000u) & 0xFFFF0000u;
                hi[j] = (short)(hu >> 16);
                lo[j] = (short)((fbits(xv[j] - bitsf(hu)) + 0x8000u) >> 16);
            }
            *(bf8_t*)&XsH[(tid >> 2) * 32 + q2x * 8] = hi;
            *(bf8_t*)&XsL[(tid >> 2) * 32 + q2x * 8] = lo;
        }
        __syncthreads();

        bf8_t wH[4], wL[4];
#pragma unroll
        for (int ns = 0; ns < 4; ++ns) {
            int n = wv * 64 + ns * 16 + l15;
            wH[ns] = *(const bf8_t*)&WsH[n * 32 + q2r * 8];
            wL[ns] = *(const bf8_t*)&WsL[n * 32 + q2r * 8];
        }
        __builtin_amdgcn_s_setprio(1);
#pragma unroll
        for (int t = 0; t < 4; ++t) {
            bf8_t xH = *(const bf8_t*)&XsH[(t * 16 + l15) * 32 + q2r * 8];
            bf8_t xL = *(const bf8_t*)&XsL[(t * 16 + l15) * 32 + q2r * 8];
#pragma unroll
            for (int ns = 0; ns < 4; ++ns) {
                f4_t c = acc[t][ns];
                if (a < 2) {
                    c = __builtin_amdgcn_mfma_f32_16x16x32_bf16(wH[ns], xH, c, 0, 0, 0);
                    c = __builtin_amdgcn_mfma_f32_16x16x32_bf16(wL[ns], xH, c, 0, 0, 0);
                    c = __builtin_amdgcn_mfma_f32_16x16x32_bf16(wH[ns], xL, c, 0, 0, 0);
                } else {
                    c = __builtin_amdgcn_mfma_f32_16x16x32_bf16(xH, wH[ns], c, 0, 0, 0);
                    c = __builtin_amdgcn_mfma_f32_16x16x32_bf16(xH, wL[ns], c, 0, 0, 0);
                    c = __builtin_amdgcn_mfma_f32_16x16x32_bf16(xL, wH[ns], c, 0, 0, 0);
                }
                acc[t][ns] = c;
            }
        }
        __builtin_amdgcn_s_setprio(0);
    }

    // ---- epilogue ----
    const int b  = m0 >> 10;
    const int sB = m0 & 1023;
    if (a < 2) {
        short* dH = (a == 0) ? qpH : kpH;
        short* dL = (a == 0) ? qpL : kpL;
        const float* mbp = mask + (size_t)b * 1024;
#pragma unroll
        for (int t = 0; t < 4; ++t) {
            int s = sB + t * 16 + l15;
            // Q: fold exp2 conversion; K: fold mask (zero masked key rows)
            const float scale = (a == 0) ? LOG2E : mbp[s];
#pragma unroll
            for (int ns = 0; ns < 4; ++ns) {
                int nw = wv * 64 + ns * 16 + quad * 4;
                int h = nw >> 5, k0 = nw & 31;
                unsigned hu[4], lu[4];
#pragma unroll
                for (int r = 0; r < 4; ++r) {
                    float x = acc[t][ns][r] * scale;
                    unsigned h32 = fbits(x) + 0x8000u;
                    hu[r] = h32;
                    float hf = bitsf(h32 & 0xFFFF0000u);
                    lu[r] = fbits(x - hf) + 0x8000u;
                }
                uint2 hp = make_uint2(__builtin_amdgcn_perm(hu[1], hu[0], PSEL),
                                      __builtin_amdgcn_perm(hu[3], hu[2], PSEL));
                uint2 lp = make_uint2(__builtin_amdgcn_perm(lu[1], lu[0], PSEL),
                                      __builtin_amdgcn_perm(lu[3], lu[2], PSEL));
                size_t off = ((size_t)(b * 8 + h) * 1024 + s) * 32 + k0;
                *(uint2*)&dH[off] = hp;
                *(uint2*)&dL[off] = lp;
            }
        }
    } else {
#pragma unroll
        for (int t = 0; t < 4; ++t) {
            int sr = sB + t * 16 + quad * 4;
#pragma unroll
            for (int ns = 0; ns < 4; ++ns) {
                int n = wv * 64 + ns * 16 + l15;
                int h = n >> 5, k = n & 31;
                unsigned eu[4];
#pragma unroll
                for (int r = 0; r < 4; ++r) eu[r] = fbits(acc[t][ns][r]) + 0x8000u;
                uint2 pk = make_uint2(__builtin_amdgcn_perm(eu[1], eu[0], PSEL),
                                      __builtin_amdgcn_perm(eu[3], eu[2], PSEL));
                *(uint2*)&vpT[((size_t)(b * 8 + h) * 32 + k) * 1024 + sr] = pk;
            }
        }
    }
}

// ---------------------------------------------------------------------------
// attn: block = 128 queries (4 waves x 32 q), 16 k-tiles of 64 keys.
// Mask pre-folded into K; no online max. 2-phase prefetch double-buffer,
// ONE barrier per iteration. K LDS XOR-swizzled both sides (T2).
// XCD-contiguous bh assignment (bijective).
// ---------------------------------------------------------------------------
__global__ __launch_bounds__(256) void attn_kernel(
    const short* __restrict__ qpH, const short* __restrict__ qpL,
    const short* __restrict__ kpH, const short* __restrict__ kpL,
    const short* __restrict__ vpT, float* __restrict__ out)
{
    __shared__ __align__(16) short KsH[2][64 * 32];
    __shared__ __align__(16) short KsL[2][64 * 32];
    __shared__ __align__(16) short VsT[2][32 * 72];

    const int tid  = threadIdx.x;
    const int lane = tid & 63;
    const int wv   = tid >> 6;
    const int l15  = lane & 15;
    const int quad = lane >> 4;
    const int q2r  = quad ^ ((l15 >> 1) & 3);          // swizzled K-read slice
    const int q2s  = (lane & 3) ^ ((lane >> 3) & 3);   // swizzled gld16 source

    // launch-linear id -> XCD-contiguous (bh, qt) assignment
    const int L  = (blockIdx.z * gridDim.y + blockIdx.y) * gridDim.x + blockIdx.x;
    const int li = L >> 3;
    const int bh = (L & 7) * 32 + (li >> 3);
    const int qt = li & 7;
    const int b  = bh >> 3;
    const int h  = bh & 7;
    const int woff = qt * 128 + wv * 32;

    bf8_t qh[2], ql[2];
#pragma unroll
    for (int qs = 0; qs < 2; ++qs) {
        size_t row = (size_t)bh * 1024 + woff + qs * 16 + l15;
        qh[qs] = *(const bf8_t*)&qpH[row * 32 + quad * 8];
        ql[qs] = *(const bf8_t*)&qpL[row * 32 + quad * 8];
    }

    f4_t accO[2][2];
    f4_t accS[2];
#pragma unroll
    for (int i = 0; i < 2; ++i) {
        accS[i] = (f4_t){0.f, 0.f, 0.f, 0.f};
#pragma unroll
        for (int j = 0; j < 2; ++j) accO[i][j] = (f4_t){0.f, 0.f, 0.f, 0.f};
    }
    const bf4_t ones4 = {(short)0x3F80, (short)0x3F80, (short)0x3F80, (short)0x3F80};

    const int dv = tid >> 3, seg = tid & 7;
    const int ksrc = (lane >> 2) * 32 + q2s * 8;       // per-lane K source offset

    // ---- prologue: stage tile 0 -> buf 0 ----
    {
        size_t toff = ((size_t)bh * 1024) * 32;
        gld16(kpH + toff + wv * 512 + ksrc, (char*)KsH[0] + wv * 1024);
        gld16(kpL + toff + wv * 512 + ksrc, (char*)KsL[0] + wv * 1024);
        uint4 v0 = *(const uint4*)&vpT[((size_t)bh * 32 + dv) * 1024 + seg * 8];
        *(uint4*)&VsT[0][dv * 72 + seg * 8] = v0;
    }
    __syncthreads();

    int cur = 0;
    for (int kt = 0; kt < 16; ++kt) {
        const int nxt = cur ^ 1;

        // ---- issue staging of tile kt+1 into buf nxt (no wait here) ----
        uint4 vreg;
        if (kt < 15) {
            size_t toff = ((size_t)bh * 1024 + (kt + 1) * 64) * 32;
            gld16(kpH + toff + wv * 512 + ksrc, (char*)KsH[nxt] + wv * 1024);
            gld16(kpL + toff + wv * 512 + ksrc, (char*)KsL[nxt] + wv * 1024);
            vreg = *(const uint4*)&vpT[((size_t)bh * 32 + dv) * 1024 + (kt + 1) * 64 + seg * 8];
        }

        __builtin_amdgcn_s_setprio(1);
        // ---- scores (Q pre-scaled by log2e); swizzled K reads ----
        f4_t sc[2][4];
#pragma unroll
        for (int ks = 0; ks < 4; ++ks) {
            bf8_t kh = *(const bf8_t*)&KsH[cur][(ks * 16 + l15) * 32 + q2r * 8];
            bf8_t kl = *(const bf8_t*)&KsL[cur][(ks * 16 + l15) * 32 + q2r * 8];
#pragma unroll
            for (int qs = 0; qs < 2; ++qs) {
                f4_t c = __builtin_amdgcn_mfma_f32_16x16x32_bf16(kh, qh[qs],
                             (f4_t){0.f, 0.f, 0.f, 0.f}, 0, 0, 0);
                c = __builtin_amdgcn_mfma_f32_16x16x32_bf16(kl, qh[qs], c, 0, 0, 0);
                c = __builtin_amdgcn_mfma_f32_16x16x32_bf16(kh, ql[qs], c, 0, 0, 0);
                sc[qs][ks] = c;
            }
        }

        // ---- P = exp2(score), packed to bf16 ----
        bf4_t pf[2][4];
#pragma unroll
        for (int ks = 0; ks < 4; ++ks) {
#pragma unroll
            for (int qs = 0; qs < 2; ++qs) {
                unsigned eu[4];
#pragma unroll
                for (int r = 0; r < 4; ++r)
                    eu[r] = fbits(EXP2F(sc[qs][ks][r])) + 0x8000u;
                union { uint2 u; bf4_t v; } cv;
                cv.u = make_uint2(__builtin_amdgcn_perm(eu[1], eu[0], PSEL),
                                  __builtin_amdgcn_perm(eu[3], eu[2], PSEL));
                pf[qs][ks] = cv.v;
            }
        }

        // ---- PV + sum ----
#pragma unroll
        for (int ks = 0; ks < 4; ++ks) {
            bf4_t vf0 = *(const bf4_t*)&VsT[cur][l15 * 72 + ks * 16 + quad * 4];
            bf4_t vf1 = *(const bf4_t*)&VsT[cur][(16 + l15) * 72 + ks * 16 + quad * 4];
#pragma unroll
            for (int qs = 0; qs < 2; ++qs) {
                accO[qs][0] = __builtin_amdgcn_mfma_f32_16x16x16bf16_1k(vf0, pf[qs][ks], accO[qs][0], 0, 0, 0);
                accO[qs][1] = __builtin_amdgcn_mfma_f32_16x16x16bf16_1k(vf1, pf[qs][ks], accO[qs][1], 0, 0, 0);
                accS[qs]    = __builtin_amdgcn_mfma_f32_16x16x16bf16_1k(ones4, pf[qs][ks], accS[qs], 0, 0, 0);
            }
        }
        __builtin_amdgcn_s_setprio(0);

        // ---- deferred V write for tile kt+1 (vmcnt wait lands here) ----
        if (kt < 15) *(uint4*)&VsT[nxt][dv * 72 + seg * 8] = vreg;
        __syncthreads();
        cur = nxt;
    }

    // ---- epilogue ----
#pragma unroll
    for (int qs = 0; qs < 2; ++qs) {
        float inv = 1.0f / accS[qs][0];
        int s = woff + qs * 16 + l15;
        float* op = out + ((size_t)b * 1024 + s) * 256 + h * 32;
#pragma unroll
        for (int dvs = 0; dvs < 2; ++dvs) {
            float4 o4 = make_float4(accO[qs][dvs][0] * inv, accO[qs][dvs][1] * inv,
                                    accO[qs][dvs][2] * inv, accO[qs][dvs][3] * inv);
            *(float4*)&op[dvs * 16 + quad * 4] = o4;
        }
    }
}

// ---------------------------------------------------------------------------
extern "C" void kernel_launch(void* const* d_in, const int* in_sizes, int n_in,
                              void* d_out, int out_size, void* d_ws, size_t ws_size,
                              hipStream_t stream)
{
    const float* query = (const float*)d_in[0];
    const float* key   = (const float*)d_in[1];
    const float* value = (const float*)d_in[2];
    const float* mask  = (const float*)d_in[3];
    const float* Wq    = (const float*)d_in[4];
    const float* Wk    = (const float*)d_in[5];
    const float* Wv    = (const float*)d_in[6];
    float* out = (float*)d_out;

    const size_t per = (size_t)B_ * H_ * S_ * DK_;
    short* qpH = (short*)d_ws;
    short* qpL = qpH + per;
    short* kpH = qpL + per;
    short* kpL = kpH + per;
    short* vpT = kpL + per;
    short* WtH = vpT + per;
    short* WtL = WtH + 3 * 256 * 256;

    prep_w<<<dim3(24, 4), 256, 0, stream>>>(Wq, Wk, Wv, WtH, WtL);
    proj_kernel<<<dim3(512, 3), 256, 0, stream>>>(query, key, value, mask, WtH, WtL,
                                                  qpH, qpL, kpH, kpL, vpT);
    attn_kernel<<<dim3(8, H_, B_), 256, 0, stream>>>(qpH, qpL, kpH, kpL, vpT, out);
}

// Round 3
// 277.603 us; speedup vs baseline: 1.0236x; 1.0047x over previous
//
#include <hip/hip_runtime.h>
#include <math.h>

#define B_  32
#define S_  1024
#define D_  256
#define H_  8
#define DK_ 32
#define MASKV (-1e-30f)
#define LOG2E 1.44269504f

typedef __attribute__((ext_vector_type(4))) short bf4_t;   // 4 bf16 (2 VGPRs)
typedef __attribute__((ext_vector_type(8))) short bf8_t;   // 8 bf16 (4 VGPRs)
typedef __attribute__((ext_vector_type(4))) float f4_t;    // MFMA accumulator

__device__ __forceinline__ unsigned fbits(float x) {
    union { float f; unsigned u; } v; v.f = x; return v.u;
}
__device__ __forceinline__ float bitsf(unsigned u) {
    union { unsigned u; float f; } v; v.u = u; return v.f;
}

#if __has_builtin(__builtin_amdgcn_exp2f)
#define EXP2F(x) __builtin_amdgcn_exp2f(x)
#else
#define EXP2F(x) __expf((x) * 0.69314718f)
#endif

__device__ __forceinline__ void gld16(const void* g, void* l) {
    __builtin_amdgcn_global_load_lds(
        (const __attribute__((address_space(1))) void*)g,
        (__attribute__((address_space(3))) void*)l, 16, 0, 0);
}

// v_perm selector: D = [S1.hi16 (low half), S0.hi16 (high half)]
#define PSEL 0x07060302u

// ===========================================================================
// FRAG-PACKED LAYOUTS (lane-linear):
//  W  (per a): off = a*65536 + ((kc*16 + ng)*64 + lane)*8 + j
//              holds W[n = ng*16 + (lane&15)][d = kc*32 + (lane>>4)*8 + j]
//  Q/K (per bh): off = ((bh*64 + grp)*64 + lane)*8 + j
//              holds P[s = grp*16 + (lane&15)][dk = (lane>>4)*8 + j]
//  A wave's MFMA fragment load = 64 lanes x 16B = 1KB contiguous:
//  coalesced from global, conflict-free in LDS, no swizzle needed.
// ===========================================================================

// ---------------------------------------------------------------------------
// prep_w: W[h][d][k] fp32 -> frag-packed hi/lo bf16 (layout above).
// ---------------------------------------------------------------------------
__global__ __launch_bounds__(256) void prep_w(
    const float* __restrict__ Wq, const float* __restrict__ Wk,
    const float* __restrict__ Wv, short* __restrict__ WpH, short* __restrict__ WpL)
{
    const int a = blockIdx.x >> 3;
    const int h = blockIdx.x & 7;
    const float* W = (a == 0 ? Wq : (a == 1 ? Wk : Wv)) + (size_t)h * 256 * 32;
    const int t = threadIdx.x;
    const int k    = t & 31;                 // dk index (0..31)
    const int dgrp = t >> 5;                 // 0..7
    const int ng   = h * 2 + (k >> 4);
    const int l15  = k & 15;
#pragma unroll
    for (int jj = blockIdx.y * 2; jj < blockIdx.y * 2 + 2; ++jj) {
        const int d0 = jj * 32 + dgrp * 4;   // 4 consecutive d, kc = jj
        float x[4];
#pragma unroll
        for (int r = 0; r < 4; ++r) x[r] = W[(size_t)(d0 + r) * 32 + k];
        unsigned hu[4], lu[4];
#pragma unroll
        for (int r = 0; r < 4; ++r) {
            unsigned hb = (fbits(x[r]) + 0x8000u) & 0xFFFF0000u;
            hu[r] = hb;
            lu[r] = fbits(x[r] - bitsf(hb)) + 0x8000u;
        }
        uint2 hp = make_uint2(__builtin_amdgcn_perm(hu[1], hu[0], PSEL),
                              __builtin_amdgcn_perm(hu[3], hu[2], PSEL));
        uint2 lp = make_uint2(__builtin_amdgcn_perm(lu[1], lu[0], PSEL),
                              __builtin_amdgcn_perm(lu[3], lu[2], PSEL));
        const int quad = (d0 >> 3) & 3;
        const int jb   = d0 & 7;             // 0 or 4
        size_t off = (size_t)a * 65536
                   + ((size_t)(jj * 16 + ng) * 64 + quad * 16 + l15) * 8 + jb;
        *(uint2*)&WpH[off] = hp;
        *(uint2*)&WpL[off] = lp;
    }
}

// ---------------------------------------------------------------------------
// proj: C[32768,256] = X * Wt^T via split-bf16 MFMA. BARRIER-FREE main loop:
//  - X tile (64 rows x 256) converted to hi/lo bf16 and staged to LDS ONCE
//    in frag-packed lane-linear order (conflict-free), single __syncthreads.
//  - W fragments read directly from global (frag-packed 1KB wave loads,
//    L2-resident) -> no per-kc barriers; waves free-run, TLP hides latency.
// a<2 (Q,K): A=W, B=X; Q scaled by LOG2E, K scaled by mask[b][s] (MASKV ~= 0
//            makes reference masking == zeroing masked K rows); epilogue
//            writes frag-packed Q/K for attn.
// a==2 (V):  A=X, B=W; packed 8B stores to [bh][dv][s] (unchanged).
// ---------------------------------------------------------------------------
__global__ __launch_bounds__(256) void proj_kernel(
    const float* __restrict__ Xq, const float* __restrict__ Xk,
    const float* __restrict__ Xv, const float* __restrict__ mask,
    const short* __restrict__ WpH, const short* __restrict__ WpL,
    short* __restrict__ qpH, short* __restrict__ qpL,
    short* __restrict__ kpH, short* __restrict__ kpL,
    short* __restrict__ vpT)
{
    __shared__ __align__(16) short XsH[16384];   // 8 kc x 4 t x 64 lanes x 8
    __shared__ __align__(16) short XsL[16384];

    const int a  = blockIdx.y;
    const float* X = (a == 0 ? Xq : (a == 1 ? Xk : Xv));
    const short* WH = WpH + (size_t)a * 65536;
    const short* WL = WpL + (size_t)a * 65536;
    const int m0 = blockIdx.x * 64;

    const int tid  = threadIdx.x;
    const int lane = tid & 63;
    const int wv   = tid >> 6;
    const int l15  = lane & 15;
    const int quad = lane >> 4;

    // ---- stage X tile once: rows m0..m0+63, all 256 d, hi/lo bf16 ----
    {
        const int r     = tid >> 2;          // row 0..63
        const int dhalf = tid & 3;           // 64-d segment
        const int tix   = r >> 4;
        const int rl15  = r & 15;
        const float* xp = X + (size_t)(m0 + r) * 256 + dhalf * 64;
#pragma unroll
        for (int cc = 0; cc < 2; ++cc) {
            const int kc = dhalf * 2 + cc;
#pragma unroll
            for (int q = 0; q < 4; ++q) {
                float4 x0 = *(const float4*)(xp + cc * 32 + q * 8);
                float4 x1 = *(const float4*)(xp + cc * 32 + q * 8 + 4);
                float xv[8] = {x0.x, x0.y, x0.z, x0.w, x1.x, x1.y, x1.z, x1.w};
                bf8_t hi, lo;
#pragma unroll
                for (int j = 0; j < 8; ++j) {
                    unsigned hu = (fbits(xv[j]) + 0x8000u) & 0xFFFF0000u;
                    hi[j] = (short)(hu >> 16);
                    lo[j] = (short)((fbits(xv[j] - bitsf(hu)) + 0x8000u) >> 16);
                }
                const int off = ((kc * 4 + tix) * 64 + q * 16 + rl15) * 8;
                *(bf8_t*)&XsH[off] = hi;
                *(bf8_t*)&XsL[off] = lo;
            }
        }
    }
    __syncthreads();

    f4_t acc[4][4];
#pragma unroll
    for (int i = 0; i < 4; ++i)
#pragma unroll
        for (int j = 0; j < 4; ++j) acc[i][j] = (f4_t){0.f, 0.f, 0.f, 0.f};

    // ---- barrier-free MFMA loop ----
#pragma unroll
    for (int kc = 0; kc < 8; ++kc) {
        bf8_t xH[4], xL[4];
#pragma unroll
        for (int t = 0; t < 4; ++t) {
            xH[t] = *(const bf8_t*)&XsH[((kc * 4 + t) * 64 + lane) * 8];
            xL[t] = *(const bf8_t*)&XsL[((kc * 4 + t) * 64 + lane) * 8];
        }
#pragma unroll
        for (int ns = 0; ns < 4; ++ns) {
            const size_t wo = ((size_t)(kc * 16 + wv * 4 + ns) * 64 + lane) * 8;
            bf8_t wh = *(const bf8_t*)&WH[wo];
            bf8_t wl = *(const bf8_t*)&WL[wo];
#pragma unroll
            for (int t = 0; t < 4; ++t) {
                f4_t c = acc[t][ns];
                if (a < 2) {
                    c = __builtin_amdgcn_mfma_f32_16x16x32_bf16(wh, xH[t], c, 0, 0, 0);
                    c = __builtin_amdgcn_mfma_f32_16x16x32_bf16(wl, xH[t], c, 0, 0, 0);
                    c = __builtin_amdgcn_mfma_f32_16x16x32_bf16(wh, xL[t], c, 0, 0, 0);
                } else {
                    c = __builtin_amdgcn_mfma_f32_16x16x32_bf16(xH[t], wh, c, 0, 0, 0);
                    c = __builtin_amdgcn_mfma_f32_16x16x32_bf16(xH[t], wl, c, 0, 0, 0);
                    c = __builtin_amdgcn_mfma_f32_16x16x32_bf16(xL[t], wh, c, 0, 0, 0);
                }
                acc[t][ns] = c;
            }
        }
    }

    // ---- epilogue ----
    const int b  = m0 >> 10;
    const int sB = m0 & 1023;
    if (a < 2) {
        short* dH = (a == 0) ? qpH : kpH;
        short* dL = (a == 0) ? qpL : kpL;
        const float* mbp = mask + (size_t)b * 1024;
#pragma unroll
        for (int t = 0; t < 4; ++t) {
            const int s = sB + t * 16 + l15;
            // Q: fold exp2 conversion; K: fold mask (zero masked key rows)
            const float scale = (a == 0) ? LOG2E : mbp[s];
            const int grp = (sB >> 4) + t;   // s >> 4
#pragma unroll
            for (int ns = 0; ns < 4; ++ns) {
                const int h_    = wv * 2 + (ns >> 1);
                const int quadA = (ns & 1) * 2 + (quad >> 1);
                const int jb    = (quad & 1) * 4;
                unsigned hu[4], lu[4];
#pragma unroll
                for (int r = 0; r < 4; ++r) {
                    float x = acc[t][ns][r] * scale;
                    unsigned h32 = fbits(x) + 0x8000u;
                    hu[r] = h32;
                    float hf = bitsf(h32 & 0xFFFF0000u);
                    lu[r] = fbits(x - hf) + 0x8000u;
                }
                uint2 hp = make_uint2(__builtin_amdgcn_perm(hu[1], hu[0], PSEL),
                                      __builtin_amdgcn_perm(hu[3], hu[2], PSEL));
                uint2 lp = make_uint2(__builtin_amdgcn_perm(lu[1], lu[0], PSEL),
                                      __builtin_amdgcn_perm(lu[3], lu[2], PSEL));
                size_t off = (((size_t)(b * 8 + h_) * 64 + grp) * 64
                              + quadA * 16 + l15) * 8 + jb;
                *(uint2*)&dH[off] = hp;
                *(uint2*)&dL[off] = lp;
            }
        }
    } else {
#pragma unroll
        for (int t = 0; t < 4; ++t) {
            int sr = sB + t * 16 + quad * 4;
#pragma unroll
            for (int ns = 0; ns < 4; ++ns) {
                int n = wv * 64 + ns * 16 + l15;
                int h = n >> 5, k = n & 31;
                unsigned eu[4];
#pragma unroll
                for (int r = 0; r < 4; ++r) eu[r] = fbits(acc[t][ns][r]) + 0x8000u;
                uint2 pk = make_uint2(__builtin_amdgcn_perm(eu[1], eu[0], PSEL),
                                      __builtin_amdgcn_perm(eu[3], eu[2], PSEL));
                *(uint2*)&vpT[((size_t)(b * 8 + h) * 32 + k) * 1024 + sr] = pk;
            }
        }
    }
}

// ---------------------------------------------------------------------------
// attn: block = 128 queries (4 waves x 32 q), 16 k-tiles of 64 keys.
// Mask pre-folded into K; no online max. 2-phase prefetch double-buffer,
// ONE barrier per iteration. Q/K are frag-packed: staging is a pure linear
// gld16 copy and all K ds_reads are lane-linear (conflict-free, no swizzle).
// XCD-contiguous bh assignment (bijective).
// ---------------------------------------------------------------------------
__global__ __launch_bounds__(256) void attn_kernel(
    const short* __restrict__ qpH, const short* __restrict__ qpL,
    const short* __restrict__ kpH, const short* __restrict__ kpL,
    const short* __restrict__ vpT, float* __restrict__ out)
{
    __shared__ __align__(16) short KsH[2][2048];   // kt-tile: 4 ks x 64 lanes x 8
    __shared__ __align__(16) short KsL[2][2048];
    __shared__ __align__(16) short VsT[2][32 * 72];

    const int tid  = threadIdx.x;
    const int lane = tid & 63;
    const int wv   = tid >> 6;
    const int l15  = lane & 15;
    const int quad = lane >> 4;

    // launch-linear id -> XCD-contiguous (bh, qt) assignment
    const int L  = (blockIdx.z * gridDim.y + blockIdx.y) * gridDim.x + blockIdx.x;
    const int li = L >> 3;
    const int bh = (L & 7) * 32 + (li >> 3);
    const int qt = li & 7;
    const int b  = bh >> 3;
    const int h  = bh & 7;
    const int woff = qt * 128 + wv * 32;

    bf8_t qh[2], ql[2];
#pragma unroll
    for (int qs = 0; qs < 2; ++qs) {
        const int grp = qt * 8 + wv * 2 + qs;      // (woff + qs*16) >> 4
        size_t off = (((size_t)bh * 64 + grp) * 64 + lane) * 8;
        qh[qs] = *(const bf8_t*)&qpH[off];
        ql[qs] = *(const bf8_t*)&qpL[off];
    }

    f4_t accO[2][2];
    f4_t accS[2];
#pragma unroll
    for (int i = 0; i < 2; ++i) {
        accS[i] = (f4_t){0.f, 0.f, 0.f, 0.f};
#pragma unroll
        for (int j = 0; j < 2; ++j) accO[i][j] = (f4_t){0.f, 0.f, 0.f, 0.f};
    }
    const bf4_t ones4 = {(short)0x3F80, (short)0x3F80, (short)0x3F80, (short)0x3F80};

    const int dv = tid >> 3, seg = tid & 7;

    // ---- prologue: stage tile 0 -> buf 0 (linear frag-packed copy) ----
    {
        size_t toff = ((size_t)bh * 64) * 512;     // kt = 0
        gld16(kpH + toff + wv * 512 + lane * 8, (char*)KsH[0] + wv * 1024);
        gld16(kpL + toff + wv * 512 + lane * 8, (char*)KsL[0] + wv * 1024);
        uint4 v0 = *(const uint4*)&vpT[((size_t)bh * 32 + dv) * 1024 + seg * 8];
        *(uint4*)&VsT[0][dv * 72 + seg * 8] = v0;
    }
    __syncthreads();

    int cur = 0;
    for (int kt = 0; kt < 16; ++kt) {
        const int nxt = cur ^ 1;

        // ---- issue staging of tile kt+1 into buf nxt (no wait here) ----
        uint4 vreg;
        if (kt < 15) {
            size_t toff = ((size_t)bh * 64 + (kt + 1) * 4) * 512;
            gld16(kpH + toff + wv * 512 + lane * 8, (char*)KsH[nxt] + wv * 1024);
            gld16(kpL + toff + wv * 512 + lane * 8, (char*)KsL[nxt] + wv * 1024);
            vreg = *(const uint4*)&vpT[((size_t)bh * 32 + dv) * 1024 + (kt + 1) * 64 + seg * 8];
        }

        __builtin_amdgcn_s_setprio(1);
        // ---- scores (Q pre-scaled by log2e); lane-linear K reads ----
        f4_t sc[2][4];
#pragma unroll
        for (int ks = 0; ks < 4; ++ks) {
            bf8_t kh = *(const bf8_t*)&KsH[cur][ks * 512 + lane * 8];
            bf8_t kl = *(const bf8_t*)&KsL[cur][ks * 512 + lane * 8];
#pragma unroll
            for (int qs = 0; qs < 2; ++qs) {
                f4_t c = __builtin_amdgcn_mfma_f32_16x16x32_bf16(kh, qh[qs],
                             (f4_t){0.f, 0.f, 0.f, 0.f}, 0, 0, 0);
                c = __builtin_amdgcn_mfma_f32_16x16x32_bf16(kl, qh[qs], c, 0, 0, 0);
                c = __builtin_amdgcn_mfma_f32_16x16x32_bf16(kh, ql[qs], c, 0, 0, 0);
                sc[qs][ks] = c;
            }
        }

        // ---- P = exp2(score), packed to bf16 ----
        bf4_t pf[2][4];
#pragma unroll
        for (int ks = 0; ks < 4; ++ks) {
#pragma unroll
            for (int qs = 0; qs < 2; ++qs) {
                unsigned eu[4];
#pragma unroll
                for (int r = 0; r < 4; ++r)
                    eu[r] = fbits(EXP2F(sc[qs][ks][r])) + 0x8000u;
                union { uint2 u; bf4_t v; } cv;
                cv.u = make_uint2(__builtin_amdgcn_perm(eu[1], eu[0], PSEL),
                                  __builtin_amdgcn_perm(eu[3], eu[2], PSEL));
                pf[qs][ks] = cv.v;
            }
        }

        // ---- PV + sum ----
#pragma unroll
        for (int ks = 0; ks < 4; ++ks) {
            bf4_t vf0 = *(const bf4_t*)&VsT[cur][l15 * 72 + ks * 16 + quad * 4];
            bf4_t vf1 = *(const bf4_t*)&VsT[cur][(16 + l15) * 72 + ks * 16 + quad * 4];
#pragma unroll
            for (int qs = 0; qs < 2; ++qs) {
                accO[qs][0] = __builtin_amdgcn_mfma_f32_16x16x16bf16_1k(vf0, pf[qs][ks], accO[qs][0], 0, 0, 0);
                accO[qs][1] = __builtin_amdgcn_mfma_f32_16x16x16bf16_1k(vf1, pf[qs][ks], accO[qs][1], 0, 0, 0);
                accS[qs]    = __builtin_amdgcn_mfma_f32_16x16x16bf16_1k(ones4, pf[qs][ks], accS[qs], 0, 0, 0);
            }
        }
        __builtin_amdgcn_s_setprio(0);

        // ---- deferred V write for tile kt+1 (vmcnt wait lands here) ----
        if (kt < 15) *(uint4*)&VsT[nxt][dv * 72 + seg * 8] = vreg;
        __syncthreads();
        cur = nxt;
    }

    // ---- epilogue ----
#pragma unroll
    for (int qs = 0; qs < 2; ++qs) {
        float inv = 1.0f / accS[qs][0];
        int s = woff + qs * 16 + l15;
        float* op = out + ((size_t)b * 1024 + s) * 256 + h * 32;
#pragma unroll
        for (int dvs = 0; dvs < 2; ++dvs) {
            float4 o4 = make_float4(accO[qs][dvs][0] * inv, accO[qs][dvs][1] * inv,
                                    accO[qs][dvs][2] * inv, accO[qs][dvs][3] * inv);
            *(float4*)&op[dvs * 16 + quad * 4] = o4;
        }
    }
}

// ---------------------------------------------------------------------------
extern "C" void kernel_launch(void* const* d_in, const int* in_sizes, int n_in,
                              void* d_out, int out_size, void* d_ws, size_t ws_size,
                              hipStream_t stream)
{
    const float* query = (const float*)d_in[0];
    const float* key   = (const float*)d_in[1];
    const float* value = (const float*)d_in[2];
    const float* mask  = (const float*)d_in[3];
    const float* Wq    = (const float*)d_in[4];
    const float* Wk    = (const float*)d_in[5];
    const float* Wv    = (const float*)d_in[6];
    float* out = (float*)d_out;

    const size_t per = (size_t)B_ * H_ * S_ * DK_;
    short* qpH = (short*)d_ws;
    short* qpL = qpH + per;
    short* kpH = qpL + per;
    short* kpL = kpH + per;
    short* vpT = kpL + per;
    short* WpH = vpT + per;
    short* WpL = WpH + 3 * 256 * 256;

    prep_w<<<dim3(24, 4), 256, 0, stream>>>(Wq, Wk, Wv, WpH, WpL);
    proj_kernel<<<dim3(512, 3), 256, 0, stream>>>(query, key, value, mask, WpH, WpL,
                                                  qpH, qpL, kpH, kpL, vpT);
    attn_kernel<<<dim3(8, H_, B_), 256, 0, stream>>>(qpH, qpL, kpH, kpL, vpT, out);
}

// Round 5
// 276.970 us; speedup vs baseline: 1.0260x; 1.0023x over previous
//
#include <hip/hip_runtime.h>
#include <math.h>

#define B_  32
#define S_  1024
#define D_  256
#define H_  8
#define DK_ 32
#define MASKV (-1e-30f)
#define LOG2E 1.44269504f

typedef __attribute__((ext_vector_type(4))) short bf4_t;   // 4 bf16 (2 VGPRs)
typedef __attribute__((ext_vector_type(8))) short bf8_t;   // 8 bf16 (4 VGPRs)
typedef __attribute__((ext_vector_type(4))) float f4_t;    // MFMA accumulator

__device__ __forceinline__ unsigned fbits(float x) {
    union { float f; unsigned u; } v; v.f = x; return v.u;
}
__device__ __forceinline__ float bitsf(unsigned u) {
    union { unsigned u; float f; } v; v.u = u; return v.f;
}

#if __has_builtin(__builtin_amdgcn_exp2f)
#define EXP2F(x) __builtin_amdgcn_exp2f(x)
#else
#define EXP2F(x) __expf((x) * 0.69314718f)
#endif

__device__ __forceinline__ void gld16(const void* g, void* l) {
    __builtin_amdgcn_global_load_lds(
        (const __attribute__((address_space(1))) void*)g,
        (__attribute__((address_space(3))) void*)l, 16, 0, 0);
}

// v_perm selector: D = [S1.hi16 (low half), S0.hi16 (high half)]
#define PSEL 0x07060302u

// ===========================================================================
// FRAG-PACKED LAYOUTS (lane-linear):
//  W  (per a): off = a*65536 + ((kc*16 + ng)*64 + lane)*8 + j
//  Q/K (per bh): off = ((bh*64 + grp)*64 + lane)*8 + j
//  A wave's MFMA fragment load = 64 lanes x 16B = 1KB contiguous.
// ===========================================================================

// ---------------------------------------------------------------------------
// prep_w: W[h][d][k] fp32 -> frag-packed hi/lo bf16.
// ---------------------------------------------------------------------------
__global__ __launch_bounds__(256) void prep_w(
    const float* __restrict__ Wq, const float* __restrict__ Wk,
    const float* __restrict__ Wv, short* __restrict__ WpH, short* __restrict__ WpL)
{
    const int a = blockIdx.x >> 3;
    const int h = blockIdx.x & 7;
    const float* W = (a == 0 ? Wq : (a == 1 ? Wk : Wv)) + (size_t)h * 256 * 32;
    const int t = threadIdx.x;
    const int k    = t & 31;
    const int dgrp = t >> 5;
    const int ng   = h * 2 + (k >> 4);
    const int l15  = k & 15;
#pragma unroll
    for (int jj = blockIdx.y * 2; jj < blockIdx.y * 2 + 2; ++jj) {
        const int d0 = jj * 32 + dgrp * 4;
        float x[4];
#pragma unroll
        for (int r = 0; r < 4; ++r) x[r] = W[(size_t)(d0 + r) * 32 + k];
        unsigned hu[4], lu[4];
#pragma unroll
        for (int r = 0; r < 4; ++r) {
            unsigned hb = (fbits(x[r]) + 0x8000u) & 0xFFFF0000u;
            hu[r] = hb;
            lu[r] = fbits(x[r] - bitsf(hb)) + 0x8000u;
        }
        uint2 hp = make_uint2(__builtin_amdgcn_perm(hu[1], hu[0], PSEL),
                              __builtin_amdgcn_perm(hu[3], hu[2], PSEL));
        uint2 lp = make_uint2(__builtin_amdgcn_perm(lu[1], lu[0], PSEL),
                              __builtin_amdgcn_perm(lu[3], lu[2], PSEL));
        const int quad = (d0 >> 3) & 3;
        const int jb   = d0 & 7;
        size_t off = (size_t)a * 65536
                   + ((size_t)(jj * 16 + ng) * 64 + quad * 16 + l15) * 8 + jb;
        *(uint2*)&WpH[off] = hp;
        *(uint2*)&WpL[off] = lp;
    }
}

// ---------------------------------------------------------------------------
// proj: C[32768,256] = X * Wt^T via split-bf16 MFMA.
//  - X staged to LDS in TWO kc-halves (32 KB total -> ~5 blocks/CU) in
//    frag-packed lane-linear order; 4 barriers per block.
//  - W fragments read directly from global (frag-packed 1KB wave loads,
//    L2-resident); TLP hides the latency.
// a<2 (Q,K): Q scaled by LOG2E, K scaled by mask (zeroes masked key rows);
//            epilogue writes frag-packed Q/K for attn.
// a==2 (V):  packed 8B stores to [bh][dv][s].
// ---------------------------------------------------------------------------
__global__ __launch_bounds__(256) void proj_kernel(
    const float* __restrict__ Xq, const float* __restrict__ Xk,
    const float* __restrict__ Xv, const float* __restrict__ mask,
    const short* __restrict__ WpH, const short* __restrict__ WpL,
    short* __restrict__ qpH, short* __restrict__ qpL,
    short* __restrict__ kpH, short* __restrict__ kpL,
    short* __restrict__ vpT)
{
    __shared__ __align__(16) short XsH[8192];   // 4 kc x 4 t x 64 lanes x 8
    __shared__ __align__(16) short XsL[8192];

    const int a  = blockIdx.y;
    const float* X = (a == 0 ? Xq : (a == 1 ? Xk : Xv));
    const short* WH = WpH + (size_t)a * 65536;
    const short* WL = WpL + (size_t)a * 65536;
    const int m0 = blockIdx.x * 64;

    const int tid  = threadIdx.x;
    const int lane = tid & 63;
    const int wv   = tid >> 6;
    const int l15  = lane & 15;
    const int quad = lane >> 4;

    f4_t acc[4][4];
#pragma unroll
    for (int i = 0; i < 4; ++i)
#pragma unroll
        for (int j = 0; j < 4; ++j) acc[i][j] = (f4_t){0.f, 0.f, 0.f, 0.f};

    const int r    = tid >> 2;               // row 0..63
    const int dseg = tid & 3;                // local kc
    const int tix  = r >> 4;
    const int rl15 = r & 15;

    for (int h2 = 0; h2 < 2; ++h2) {
        __syncthreads();                     // previous compute done
        // ---- stage X half (fp32 -> hi/lo, frag-packed lane-linear) ----
        {
            const float* xp = X + (size_t)(m0 + r) * 256 + h2 * 128 + dseg * 32;
#pragma unroll
            for (int q = 0; q < 4; ++q) {
                float4 x0 = *(const float4*)(xp + q * 8);
                float4 x1 = *(const float4*)(xp + q * 8 + 4);
                float xv[8] = {x0.x, x0.y, x0.z, x0.w, x1.x, x1.y, x1.z, x1.w};
                bf8_t hi, lo;
#pragma unroll
                for (int j = 0; j < 8; ++j) {
                    unsigned hu = (fbits(xv[j]) + 0x8000u) & 0xFFFF0000u;
                    hi[j] = (short)(hu >> 16);
                    lo[j] = (short)((fbits(xv[j] - bitsf(hu)) + 0x8000u) >> 16);
                }
                const int off = ((dseg * 4 + tix) * 64 + q * 16 + rl15) * 8;
                *(bf8_t*)&XsH[off] = hi;
                *(bf8_t*)&XsL[off] = lo;
            }
        }
        __syncthreads();

        // ---- compute this half: 4 kc, W direct from global ----
#pragma unroll
        for (int kcl = 0; kcl < 4; ++kcl) {
            const int kc = h2 * 4 + kcl;
            bf8_t xH[4], xL[4];
#pragma unroll
            for (int t = 0; t < 4; ++t) {
                xH[t] = *(const bf8_t*)&XsH[((kcl * 4 + t) * 64 + lane) * 8];
                xL[t] = *(const bf8_t*)&XsL[((kcl * 4 + t) * 64 + lane) * 8];
            }
#pragma unroll
            for (int ns = 0; ns < 4; ++ns) {
                const size_t wo = ((size_t)(kc * 16 + wv * 4 + ns) * 64 + lane) * 8;
                bf8_t wh = *(const bf8_t*)&WH[wo];
                bf8_t wl = *(const bf8_t*)&WL[wo];
#pragma unroll
                for (int t = 0; t < 4; ++t) {
                    f4_t c = acc[t][ns];
                    if (a < 2) {
                        c = __builtin_amdgcn_mfma_f32_16x16x32_bf16(wh, xH[t], c, 0, 0, 0);
                        c = __builtin_amdgcn_mfma_f32_16x16x32_bf16(wl, xH[t], c, 0, 0, 0);
                        c = __builtin_amdgcn_mfma_f32_16x16x32_bf16(wh, xL[t], c, 0, 0, 0);
                    } else {
                        c = __builtin_amdgcn_mfma_f32_16x16x32_bf16(xH[t], wh, c, 0, 0, 0);
                        c = __builtin_amdgcn_mfma_f32_16x16x32_bf16(xH[t], wl, c, 0, 0, 0);
                        c = __builtin_amdgcn_mfma_f32_16x16x32_bf16(xL[t], wh, c, 0, 0, 0);
                    }
                    acc[t][ns] = c;
                }
            }
        }
    }

    // ---- epilogue ----
    const int b  = m0 >> 10;
    const int sB = m0 & 1023;
    if (a < 2) {
        short* dH = (a == 0) ? qpH : kpH;
        short* dL = (a == 0) ? qpL : kpL;
        const float* mbp = mask + (size_t)b * 1024;
#pragma unroll
        for (int t = 0; t < 4; ++t) {
            const int s = sB + t * 16 + l15;
            const float scale = (a == 0) ? LOG2E : mbp[s];
            const int grp = (sB >> 4) + t;
#pragma unroll
            for (int ns = 0; ns < 4; ++ns) {
                const int h_    = wv * 2 + (ns >> 1);
                const int quadA = (ns & 1) * 2 + (quad >> 1);
                const int jb    = (quad & 1) * 4;
                unsigned hu[4], lu[4];
#pragma unroll
                for (int rr = 0; rr < 4; ++rr) {
                    float x = acc[t][ns][rr] * scale;
                    unsigned h32 = fbits(x) + 0x8000u;
                    hu[rr] = h32;
                    float hf = bitsf(h32 & 0xFFFF0000u);
                    lu[rr] = fbits(x - hf) + 0x8000u;
                }
                uint2 hp = make_uint2(__builtin_amdgcn_perm(hu[1], hu[0], PSEL),
                                      __builtin_amdgcn_perm(hu[3], hu[2], PSEL));
                uint2 lp = make_uint2(__builtin_amdgcn_perm(lu[1], lu[0], PSEL),
                                      __builtin_amdgcn_perm(lu[3], lu[2], PSEL));
                size_t off = (((size_t)(b * 8 + h_) * 64 + grp) * 64
                              + quadA * 16 + l15) * 8 + jb;
                *(uint2*)&dH[off] = hp;
                *(uint2*)&dL[off] = lp;
            }
        }
    } else {
#pragma unroll
        for (int t = 0; t < 4; ++t) {
            int sr = sB + t * 16 + quad * 4;
#pragma unroll
            for (int ns = 0; ns < 4; ++ns) {
                int n = wv * 64 + ns * 16 + l15;
                int h = n >> 5, k = n & 31;
                unsigned eu[4];
#pragma unroll
                for (int rr = 0; rr < 4; ++rr) eu[rr] = fbits(acc[t][ns][rr]) + 0x8000u;
                uint2 pk = make_uint2(__builtin_amdgcn_perm(eu[1], eu[0], PSEL),
                                      __builtin_amdgcn_perm(eu[3], eu[2], PSEL));
                *(uint2*)&vpT[((size_t)(b * 8 + h) * 32 + k) * 1024 + sr] = pk;
            }
        }
    }
}

// ---------------------------------------------------------------------------
// attn: EXACT round-3 structure (verified passing). block = 128 queries
// (4 waves x 32 q), 16 k-tiles of 64 keys. Mask pre-folded into K; no
// online max. 2-phase prefetch double-buffer, ONE barrier per iteration.
// Q/K frag-packed: staging is a pure linear gld16 copy, lane-linear
// ds_reads. XCD-contiguous bh assignment (bijective).
// ---------------------------------------------------------------------------
__global__ __launch_bounds__(256) void attn_kernel(
    const short* __restrict__ qpH, const short* __restrict__ qpL,
    const short* __restrict__ kpH, const short* __restrict__ kpL,
    const short* __restrict__ vpT, float* __restrict__ out)
{
    __shared__ __align__(16) short KsH[2][2048];   // kt-tile: 4 ks x 64 lanes x 8
    __shared__ __align__(16) short KsL[2][2048];
    __shared__ __align__(16) short VsT[2][32 * 72];

    const int tid  = threadIdx.x;
    const int lane = tid & 63;
    const int wv   = tid >> 6;
    const int l15  = lane & 15;
    const int quad = lane >> 4;

    // launch-linear id -> XCD-contiguous (bh, qt) assignment
    const int L  = (blockIdx.z * gridDim.y + blockIdx.y) * gridDim.x + blockIdx.x;
    const int li = L >> 3;
    const int bh = (L & 7) * 32 + (li >> 3);
    const int qt = li & 7;
    const int b  = bh >> 3;
    const int h  = bh & 7;
    const int woff = qt * 128 + wv * 32;

    bf8_t qh[2], ql[2];
#pragma unroll
    for (int qs = 0; qs < 2; ++qs) {
        const int grp = qt * 8 + wv * 2 + qs;      // (woff + qs*16) >> 4
        size_t off = (((size_t)bh * 64 + grp) * 64 + lane) * 8;
        qh[qs] = *(const bf8_t*)&qpH[off];
        ql[qs] = *(const bf8_t*)&qpL[off];
    }

    f4_t accO[2][2];
    f4_t accS[2];
#pragma unroll
    for (int i = 0; i < 2; ++i) {
        accS[i] = (f4_t){0.f, 0.f, 0.f, 0.f};
#pragma unroll
        for (int j = 0; j < 2; ++j) accO[i][j] = (f4_t){0.f, 0.f, 0.f, 0.f};
    }
    const bf4_t ones4 = {(short)0x3F80, (short)0x3F80, (short)0x3F80, (short)0x3F80};

    const int dv = tid >> 3, seg = tid & 7;

    // ---- prologue: stage tile 0 -> buf 0 (linear frag-packed copy) ----
    {
        size_t toff = ((size_t)bh * 64) * 512;     // kt = 0
        gld16(kpH + toff + wv * 512 + lane * 8, (char*)KsH[0] + wv * 1024);
        gld16(kpL + toff + wv * 512 + lane * 8, (char*)KsL[0] + wv * 1024);
        uint4 v0 = *(const uint4*)&vpT[((size_t)bh * 32 + dv) * 1024 + seg * 8];
        *(uint4*)&VsT[0][dv * 72 + seg * 8] = v0;
    }
    __syncthreads();

    int cur = 0;
    for (int kt = 0; kt < 16; ++kt) {
        const int nxt = cur ^ 1;

        // ---- issue staging of tile kt+1 into buf nxt (no wait here) ----
        uint4 vreg;
        if (kt < 15) {
            size_t toff = ((size_t)bh * 64 + (kt + 1) * 4) * 512;
            gld16(kpH + toff + wv * 512 + lane * 8, (char*)KsH[nxt] + wv * 1024);
            gld16(kpL + toff + wv * 512 + lane * 8, (char*)KsL[nxt] + wv * 1024);
            vreg = *(const uint4*)&vpT[((size_t)bh * 32 + dv) * 1024 + (kt + 1) * 64 + seg * 8];
        }

        __builtin_amdgcn_s_setprio(1);
        // ---- scores (Q pre-scaled by log2e); lane-linear K reads ----
        f4_t sc[2][4];
#pragma unroll
        for (int ks = 0; ks < 4; ++ks) {
            bf8_t kh = *(const bf8_t*)&KsH[cur][ks * 512 + lane * 8];
            bf8_t kl = *(const bf8_t*)&KsL[cur][ks * 512 + lane * 8];
#pragma unroll
            for (int qs = 0; qs < 2; ++qs) {
                f4_t c = __builtin_amdgcn_mfma_f32_16x16x32_bf16(kh, qh[qs],
                             (f4_t){0.f, 0.f, 0.f, 0.f}, 0, 0, 0);
                c = __builtin_amdgcn_mfma_f32_16x16x32_bf16(kl, qh[qs], c, 0, 0, 0);
                c = __builtin_amdgcn_mfma_f32_16x16x32_bf16(kh, ql[qs], c, 0, 0, 0);
                sc[qs][ks] = c;
            }
        }

        // ---- P = exp2(score), packed to bf16 ----
        bf4_t pf[2][4];
#pragma unroll
        for (int ks = 0; ks < 4; ++ks) {
#pragma unroll
            for (int qs = 0; qs < 2; ++qs) {
                unsigned eu[4];
#pragma unroll
                for (int r = 0; r < 4; ++r)
                    eu[r] = fbits(EXP2F(sc[qs][ks][r])) + 0x8000u;
                union { uint2 u; bf4_t v; } cv;
                cv.u = make_uint2(__builtin_amdgcn_perm(eu[1], eu[0], PSEL),
                                  __builtin_amdgcn_perm(eu[3], eu[2], PSEL));
                pf[qs][ks] = cv.v;
            }
        }

        // ---- PV + sum ----
#pragma unroll
        for (int ks = 0; ks < 4; ++ks) {
            bf4_t vf0 = *(const bf4_t*)&VsT[cur][l15 * 72 + ks * 16 + quad * 4];
            bf4_t vf1 = *(const bf4_t*)&VsT[cur][(16 + l15) * 72 + ks * 16 + quad * 4];
#pragma unroll
            for (int qs = 0; qs < 2; ++qs) {
                accO[qs][0] = __builtin_amdgcn_mfma_f32_16x16x16bf16_1k(vf0, pf[qs][ks], accO[qs][0], 0, 0, 0);
                accO[qs][1] = __builtin_amdgcn_mfma_f32_16x16x16bf16_1k(vf1, pf[qs][ks], accO[qs][1], 0, 0, 0);
                accS[qs]    = __builtin_amdgcn_mfma_f32_16x16x16bf16_1k(ones4, pf[qs][ks], accS[qs], 0, 0, 0);
            }
        }
        __builtin_amdgcn_s_setprio(0);

        // ---- deferred V write for tile kt+1 (vmcnt wait lands here) ----
        if (kt < 15) *(uint4*)&VsT[nxt][dv * 72 + seg * 8] = vreg;
        __syncthreads();
        cur = nxt;
    }

    // ---- epilogue ----
#pragma unroll
    for (int qs = 0; qs < 2; ++qs) {
        float inv = 1.0f / accS[qs][0];
        int s = woff + qs * 16 + l15;
        float* op = out + ((size_t)b * 1024 + s) * 256 + h * 32;
#pragma unroll
        for (int dvs = 0; dvs < 2; ++dvs) {
            float4 o4 = make_float4(accO[qs][dvs][0] * inv, accO[qs][dvs][1] * inv,
                                    accO[qs][dvs][2] * inv, accO[qs][dvs][3] * inv);
            *(float4*)&op[dvs * 16 + quad * 4] = o4;
        }
    }
}

// ---------------------------------------------------------------------------
extern "C" void kernel_launch(void* const* d_in, const int* in_sizes, int n_in,
                              void* d_out, int out_size, void* d_ws, size_t ws_size,
                              hipStream_t stream)
{
    const float* query = (const float*)d_in[0];
    const float* key   = (const float*)d_in[1];
    const float* value = (const float*)d_in[2];
    const float* mask  = (const float*)d_in[3];
    const float* Wq    = (const float*)d_in[4];
    const float* Wk    = (const float*)d_in[5];
    const float* Wv    = (const float*)d_in[6];
    float* out = (float*)d_out;

    const size_t per = (size_t)B_ * H_ * S_ * DK_;
    short* qpH = (short*)d_ws;
    short* qpL = qpH + per;
    short* kpH = qpL + per;
    short* kpL = kpH + per;
    short* vpT = kpL + per;
    short* WpH = vpT + per;
    short* WpL = WpH + 3 * 256 * 256;

    prep_w<<<dim3(24, 4), 256, 0, stream>>>(Wq, Wk, Wv, WpH, WpL);
    proj_kernel<<<dim3(512, 3), 256, 0, stream>>>(query, key, value, mask, WpH, WpL,
                                                  qpH, qpL, kpH, kpL, vpT);
    attn_kernel<<<dim3(8, H_, B_), 256, 0, stream>>>(qpH, qpL, kpH, kpL, vpT, out);
}

// Round 6
// 271.950 us; speedup vs baseline: 1.0449x; 1.0185x over previous
//
#include <hip/hip_runtime.h>
#include <math.h>

#define B_  32
#define S_  1024
#define D_  256
#define H_  8
#define DK_ 32
#define MASKV (-1e-30f)
#define LOG2E 1.44269504f

typedef __attribute__((ext_vector_type(4))) short bf4_t;   // 4 bf16 (2 VGPRs)
typedef __attribute__((ext_vector_type(8))) short bf8_t;   // 8 bf16 (4 VGPRs)
typedef __attribute__((ext_vector_type(4))) float f4_t;    // MFMA accumulator

__device__ __forceinline__ unsigned fbits(float x) {
    union { float f; unsigned u; } v; v.f = x; return v.u;
}
__device__ __forceinline__ float bitsf(unsigned u) {
    union { unsigned u; float f; } v; v.u = u; return v.f;
}

#if __has_builtin(__builtin_amdgcn_exp2f)
#define EXP2F(x) __builtin_amdgcn_exp2f(x)
#else
#define EXP2F(x) __expf((x) * 0.69314718f)
#endif

__device__ __forceinline__ void gld16(const void* g, void* l) {
    __builtin_amdgcn_global_load_lds(
        (const __attribute__((address_space(1))) void*)g,
        (__attribute__((address_space(3))) void*)l, 16, 0, 0);
}

// v_perm selector: D = [S1.hi16 (low half), S0.hi16 (high half)]
#define PSEL 0x07060302u

// ===========================================================================
// FRAG-PACKED LAYOUTS (lane-linear):
//  W  (per a): off = a*65536 + ((kc*16 + ng)*64 + lane)*8 + j
//  Q/K (per bh): off = ((bh*64 + grp)*64 + lane)*8 + j
//  A wave's MFMA fragment load = 64 lanes x 16B = 1KB contiguous.
// ===========================================================================

// ---------------------------------------------------------------------------
// prep_w: W[h][d][k] fp32 -> frag-packed hi/lo bf16.  (byte-identical to r5)
// ---------------------------------------------------------------------------
__global__ __launch_bounds__(256) void prep_w(
    const float* __restrict__ Wq, const float* __restrict__ Wk,
    const float* __restrict__ Wv, short* __restrict__ WpH, short* __restrict__ WpL)
{
    const int a = blockIdx.x >> 3;
    const int h = blockIdx.x & 7;
    const float* W = (a == 0 ? Wq : (a == 1 ? Wk : Wv)) + (size_t)h * 256 * 32;
    const int t = threadIdx.x;
    const int k    = t & 31;
    const int dgrp = t >> 5;
    const int ng   = h * 2 + (k >> 4);
    const int l15  = k & 15;
#pragma unroll
    for (int jj = blockIdx.y * 2; jj < blockIdx.y * 2 + 2; ++jj) {
        const int d0 = jj * 32 + dgrp * 4;
        float x[4];
#pragma unroll
        for (int r = 0; r < 4; ++r) x[r] = W[(size_t)(d0 + r) * 32 + k];
        unsigned hu[4], lu[4];
#pragma unroll
        for (int r = 0; r < 4; ++r) {
            unsigned hb = (fbits(x[r]) + 0x8000u) & 0xFFFF0000u;
            hu[r] = hb;
            lu[r] = fbits(x[r] - bitsf(hb)) + 0x8000u;
        }
        uint2 hp = make_uint2(__builtin_amdgcn_perm(hu[1], hu[0], PSEL),
                              __builtin_amdgcn_perm(hu[3], hu[2], PSEL));
        uint2 lp = make_uint2(__builtin_amdgcn_perm(lu[1], lu[0], PSEL),
                              __builtin_amdgcn_perm(lu[3], lu[2], PSEL));
        const int quad = (d0 >> 3) & 3;
        const int jb   = d0 & 7;
        size_t off = (size_t)a * 65536
                   + ((size_t)(jj * 16 + ng) * 64 + quad * 16 + l15) * 8 + jb;
        *(uint2*)&WpH[off] = hp;
        *(uint2*)&WpL[off] = lp;
    }
}

// ---------------------------------------------------------------------------
// proj: C[32768,256] = X * Wt^T via split-bf16 MFMA.  (byte-identical to r5)
// ---------------------------------------------------------------------------
__global__ __launch_bounds__(256) void proj_kernel(
    const float* __restrict__ Xq, const float* __restrict__ Xk,
    const float* __restrict__ Xv, const float* __restrict__ mask,
    const short* __restrict__ WpH, const short* __restrict__ WpL,
    short* __restrict__ qpH, short* __restrict__ qpL,
    short* __restrict__ kpH, short* __restrict__ kpL,
    short* __restrict__ vpT)
{
    __shared__ __align__(16) short XsH[8192];   // 4 kc x 4 t x 64 lanes x 8
    __shared__ __align__(16) short XsL[8192];

    const int a  = blockIdx.y;
    const float* X = (a == 0 ? Xq : (a == 1 ? Xk : Xv));
    const short* WH = WpH + (size_t)a * 65536;
    const short* WL = WpL + (size_t)a * 65536;
    const int m0 = blockIdx.x * 64;

    const int tid  = threadIdx.x;
    const int lane = tid & 63;
    const int wv   = tid >> 6;
    const int l15  = lane & 15;
    const int quad = lane >> 4;

    f4_t acc[4][4];
#pragma unroll
    for (int i = 0; i < 4; ++i)
#pragma unroll
        for (int j = 0; j < 4; ++j) acc[i][j] = (f4_t){0.f, 0.f, 0.f, 0.f};

    const int r    = tid >> 2;               // row 0..63
    const int dseg = tid & 3;                // local kc
    const int tix  = r >> 4;
    const int rl15 = r & 15;

    for (int h2 = 0; h2 < 2; ++h2) {
        __syncthreads();                     // previous compute done
        // ---- stage X half (fp32 -> hi/lo, frag-packed lane-linear) ----
        {
            const float* xp = X + (size_t)(m0 + r) * 256 + h2 * 128 + dseg * 32;
#pragma unroll
            for (int q = 0; q < 4; ++q) {
                float4 x0 = *(const float4*)(xp + q * 8);
                float4 x1 = *(const float4*)(xp + q * 8 + 4);
                float xv[8] = {x0.x, x0.y, x0.z, x0.w, x1.x, x1.y, x1.z, x1.w};
                bf8_t hi, lo;
#pragma unroll
                for (int j = 0; j < 8; ++j) {
                    unsigned hu = (fbits(xv[j]) + 0x8000u) & 0xFFFF0000u;
                    hi[j] = (short)(hu >> 16);
                    lo[j] = (short)((fbits(xv[j] - bitsf(hu)) + 0x8000u) >> 16);
                }
                const int off = ((dseg * 4 + tix) * 64 + q * 16 + rl15) * 8;
                *(bf8_t*)&XsH[off] = hi;
                *(bf8_t*)&XsL[off] = lo;
            }
        }
        __syncthreads();

        // ---- compute this half: 4 kc, W direct from global ----
#pragma unroll
        for (int kcl = 0; kcl < 4; ++kcl) {
            const int kc = h2 * 4 + kcl;
            bf8_t xH[4], xL[4];
#pragma unroll
            for (int t = 0; t < 4; ++t) {
                xH[t] = *(const bf8_t*)&XsH[((kcl * 4 + t) * 64 + lane) * 8];
                xL[t] = *(const bf8_t*)&XsL[((kcl * 4 + t) * 64 + lane) * 8];
            }
#pragma unroll
            for (int ns = 0; ns < 4; ++ns) {
                const size_t wo = ((size_t)(kc * 16 + wv * 4 + ns) * 64 + lane) * 8;
                bf8_t wh = *(const bf8_t*)&WH[wo];
                bf8_t wl = *(const bf8_t*)&WL[wo];
#pragma unroll
                for (int t = 0; t < 4; ++t) {
                    f4_t c = acc[t][ns];
                    if (a < 2) {
                        c = __builtin_amdgcn_mfma_f32_16x16x32_bf16(wh, xH[t], c, 0, 0, 0);
                        c = __builtin_amdgcn_mfma_f32_16x16x32_bf16(wl, xH[t], c, 0, 0, 0);
                        c = __builtin_amdgcn_mfma_f32_16x16x32_bf16(wh, xL[t], c, 0, 0, 0);
                    } else {
                        c = __builtin_amdgcn_mfma_f32_16x16x32_bf16(xH[t], wh, c, 0, 0, 0);
                        c = __builtin_amdgcn_mfma_f32_16x16x32_bf16(xH[t], wl, c, 0, 0, 0);
                        c = __builtin_amdgcn_mfma_f32_16x16x32_bf16(xL[t], wh, c, 0, 0, 0);
                    }
                    acc[t][ns] = c;
                }
            }
        }
    }

    // ---- epilogue ----
    const int b  = m0 >> 10;
    const int sB = m0 & 1023;
    if (a < 2) {
        short* dH = (a == 0) ? qpH : kpH;
        short* dL = (a == 0) ? qpL : kpL;
        const float* mbp = mask + (size_t)b * 1024;
#pragma unroll
        for (int t = 0; t < 4; ++t) {
            const int s = sB + t * 16 + l15;
            const float scale = (a == 0) ? LOG2E : mbp[s];
            const int grp = (sB >> 4) + t;
#pragma unroll
            for (int ns = 0; ns < 4; ++ns) {
                const int h_    = wv * 2 + (ns >> 1);
                const int quadA = (ns & 1) * 2 + (quad >> 1);
                const int jb    = (quad & 1) * 4;
                unsigned hu[4], lu[4];
#pragma unroll
                for (int rr = 0; rr < 4; ++rr) {
                    float x = acc[t][ns][rr] * scale;
                    unsigned h32 = fbits(x) + 0x8000u;
                    hu[rr] = h32;
                    float hf = bitsf(h32 & 0xFFFF0000u);
                    lu[rr] = fbits(x - hf) + 0x8000u;
                }
                uint2 hp = make_uint2(__builtin_amdgcn_perm(hu[1], hu[0], PSEL),
                                      __builtin_amdgcn_perm(hu[3], hu[2], PSEL));
                uint2 lp = make_uint2(__builtin_amdgcn_perm(lu[1], lu[0], PSEL),
                                      __builtin_amdgcn_perm(lu[3], lu[2], PSEL));
                size_t off = (((size_t)(b * 8 + h_) * 64 + grp) * 64
                              + quadA * 16 + l15) * 8 + jb;
                *(uint2*)&dH[off] = hp;
                *(uint2*)&dL[off] = lp;
            }
        }
    } else {
#pragma unroll
        for (int t = 0; t < 4; ++t) {
            int sr = sB + t * 16 + quad * 4;
#pragma unroll
            for (int ns = 0; ns < 4; ++ns) {
                int n = wv * 64 + ns * 16 + l15;
                int h = n >> 5, k = n & 31;
                unsigned eu[4];
#pragma unroll
                for (int rr = 0; rr < 4; ++rr) eu[rr] = fbits(acc[t][ns][rr]) + 0x8000u;
                uint2 pk = make_uint2(__builtin_amdgcn_perm(eu[1], eu[0], PSEL),
                                      __builtin_amdgcn_perm(eu[3], eu[2], PSEL));
                *(uint2*)&vpT[((size_t)(b * 8 + h) * 32 + k) * 1024 + sr] = pk;
            }
        }
    }
}

// ---------------------------------------------------------------------------
// attn: block = 128 queries (4 waves x 32 q), 16 k-tiles of 64 keys.
// Mask pre-folded into K; no online max. CROSS-KT SOFTWARE PIPELINE:
// P and V fragments of tile kt-1 live in registers; per-ks the body fuses
// {QK(kt) MFMA -> PV(kt-1) MFMA -> exp/pack(kt) VALU} so MFMA and VALU
// pipes overlap instead of alternating (r3: MfmaUtil+VALUBusy == 100%,
// strictly serialized). Pack uses the PROVEN r3 perm-based bf16 round
// (bit-identical math & summation order to r3; only instruction order
// changes). Static buffer parity via macro-unrolled 2-stage loop (no
// runtime-indexed register arrays). One barrier per kt, same epochs as r3.
// ---------------------------------------------------------------------------
__global__ __launch_bounds__(256) void attn_kernel(
    const short* __restrict__ qpH, const short* __restrict__ qpL,
    const short* __restrict__ kpH, const short* __restrict__ kpL,
    const short* __restrict__ vpT, float* __restrict__ out)
{
    __shared__ __align__(16) short KsH[2][2048];   // kt-tile: 4 ks x 64 lanes x 8
    __shared__ __align__(16) short KsL[2][2048];
    __shared__ __align__(16) short VsT[2][32 * 72];

    const int tid  = threadIdx.x;
    const int lane = tid & 63;
    const int wv   = tid >> 6;
    const int l15  = lane & 15;
    const int quad = lane >> 4;

    // launch-linear id -> XCD-contiguous (bh, qt) assignment
    const int L  = (blockIdx.z * gridDim.y + blockIdx.y) * gridDim.x + blockIdx.x;
    const int li = L >> 3;
    const int bh = (L & 7) * 32 + (li >> 3);
    const int qt = li & 7;
    const int b  = bh >> 3;
    const int h  = bh & 7;
    const int woff = qt * 128 + wv * 32;

    bf8_t qh[2], ql[2];
#pragma unroll
    for (int qs = 0; qs < 2; ++qs) {
        const int grp = qt * 8 + wv * 2 + qs;      // (woff + qs*16) >> 4
        size_t off = (((size_t)bh * 64 + grp) * 64 + lane) * 8;
        qh[qs] = *(const bf8_t*)&qpH[off];
        ql[qs] = *(const bf8_t*)&qpL[off];
    }

    f4_t accO[2][2];
    f4_t accS[2];
#pragma unroll
    for (int i = 0; i < 2; ++i) {
        accS[i] = (f4_t){0.f, 0.f, 0.f, 0.f};
#pragma unroll
        for (int j = 0; j < 2; ++j) accO[i][j] = (f4_t){0.f, 0.f, 0.f, 0.f};
    }
    const bf4_t ones4 = {(short)0x3F80, (short)0x3F80, (short)0x3F80, (short)0x3F80};

    const int dv = tid >> 3, seg = tid & 7;

    bf4_t vA[8], vB[8];
    bf4_t pfA[2][4], pfB[2][4];

// one pipelined k-tile. KT: tile index; CUR: its LDS buffer (== KT&1);
// DO_STAGE: stage tile KT+1; DO_PV: run PV for tile KT-1 from VIN/PIN.
// All buffer names are static -> everything stays in registers.
#define TILE(KT, CUR, DO_STAGE, DO_PV, VIN, VOUT, PIN, POUT)                    \
    {                                                                           \
        /* 1. V(KT) frags LDS -> VOUT regs (consumed next tile) */              \
        _Pragma("unroll")                                                       \
        for (int ks = 0; ks < 4; ++ks) {                                        \
            VOUT[ks * 2]     = *(const bf4_t*)&VsT[CUR][l15 * 72 + ks * 16 + quad * 4];       \
            VOUT[ks * 2 + 1] = *(const bf4_t*)&VsT[CUR][(16 + l15) * 72 + ks * 16 + quad * 4];\
        }                                                                       \
        /* 2. issue staging of tile KT+1 into buf CUR^1 (no wait) */            \
        uint4 vreg;                                                             \
        if (DO_STAGE) {                                                         \
            size_t toff = ((size_t)bh * 64 + (size_t)((KT) + 1) * 4) * 512;     \
            gld16(kpH + toff + wv * 512 + lane * 8, (char*)KsH[(CUR) ^ 1] + wv * 1024); \
            gld16(kpL + toff + wv * 512 + lane * 8, (char*)KsL[(CUR) ^ 1] + wv * 1024); \
            vreg = *(const uint4*)&vpT[((size_t)bh * 32 + dv) * 1024            \
                                       + (size_t)((KT) + 1) * 64 + seg * 8];    \
        }                                                                       \
        __builtin_amdgcn_s_setprio(1);                                          \
        /* 3. fused per-ks: QK(KT) -> PV(KT-1) -> exp/pack(KT) */               \
        _Pragma("unroll")                                                       \
        for (int ks = 0; ks < 4; ++ks) {                                        \
            bf8_t kh = *(const bf8_t*)&KsH[CUR][ks * 512 + lane * 8];           \
            bf8_t kl = *(const bf8_t*)&KsL[CUR][ks * 512 + lane * 8];           \
            f4_t sc[2];                                                         \
            _Pragma("unroll")                                                   \
            for (int qs = 0; qs < 2; ++qs) {                                    \
                f4_t c = __builtin_amdgcn_mfma_f32_16x16x32_bf16(kh, qh[qs],    \
                             (f4_t){0.f, 0.f, 0.f, 0.f}, 0, 0, 0);              \
                c = __builtin_amdgcn_mfma_f32_16x16x32_bf16(kl, qh[qs], c, 0, 0, 0); \
                c = __builtin_amdgcn_mfma_f32_16x16x32_bf16(kh, ql[qs], c, 0, 0, 0); \
                sc[qs] = c;                                                     \
            }                                                                   \
            if (DO_PV) {                                                        \
                _Pragma("unroll")                                               \
                for (int qs = 0; qs < 2; ++qs) {                                \
                    accO[qs][0] = __builtin_amdgcn_mfma_f32_16x16x16bf16_1k(    \
                                      VIN[ks * 2], PIN[qs][ks], accO[qs][0], 0, 0, 0);     \
                    accO[qs][1] = __builtin_amdgcn_mfma_f32_16x16x16bf16_1k(    \
                                      VIN[ks * 2 + 1], PIN[qs][ks], accO[qs][1], 0, 0, 0); \
                    accS[qs]    = __builtin_amdgcn_mfma_f32_16x16x16bf16_1k(    \
                                      ones4, PIN[qs][ks], accS[qs], 0, 0, 0);   \
                }                                                               \
            }                                                                   \
            _Pragma("unroll")                                                   \
            for (int qs = 0; qs < 2; ++qs) {                                    \
                unsigned eu[4];                                                 \
                _Pragma("unroll")                                               \
                for (int r = 0; r < 4; ++r)                                     \
                    eu[r] = fbits(EXP2F(sc[qs][r])) + 0x8000u;                  \
                union { uint2 u; bf4_t v; } cv;                                 \
                cv.u = make_uint2(__builtin_amdgcn_perm(eu[1], eu[0], PSEL),    \
                                  __builtin_amdgcn_perm(eu[3], eu[2], PSEL));   \
                POUT[qs][ks] = cv.v;                                            \
            }                                                                   \
        }                                                                       \
        __builtin_amdgcn_s_setprio(0);                                          \
        /* 4. deferred V write for tile KT+1 (vmcnt wait lands here) */         \
        if (DO_STAGE) *(uint4*)&VsT[(CUR) ^ 1][dv * 72 + seg * 8] = vreg;       \
        __syncthreads();                                                        \
    }

    // ---- prologue: stage tile 0 -> buf 0 (linear frag-packed copy) ----
    {
        size_t toff = ((size_t)bh * 64) * 512;     // kt = 0
        gld16(kpH + toff + wv * 512 + lane * 8, (char*)KsH[0] + wv * 1024);
        gld16(kpL + toff + wv * 512 + lane * 8, (char*)KsL[0] + wv * 1024);
        uint4 v0 = *(const uint4*)&vpT[((size_t)bh * 32 + dv) * 1024 + seg * 8];
        *(uint4*)&VsT[0][dv * 72 + seg * 8] = v0;
    }
    __syncthreads();

    TILE(0, 0, 1, 0, vA, vA, pfA, pfA)            // fills vA = V(0), pfA = P(0)
    for (int i = 0; i < 7; ++i) {
        TILE(2 * i + 1, 1, 1, 1, vA, vB, pfA, pfB)   // PV(2i),   fills V/P(2i+1)
        TILE(2 * i + 2, 0, 1, 1, vB, vA, pfB, pfA)   // PV(2i+1), fills V/P(2i+2)
    }
    TILE(15, 1, 0, 1, vA, vB, pfA, pfB)           // PV(14), fills vB = V(15), pfB = P(15)

    // ---- drain: PV for tile 15 ----
#pragma unroll
    for (int ks = 0; ks < 4; ++ks) {
#pragma unroll
        for (int qs = 0; qs < 2; ++qs) {
            accO[qs][0] = __builtin_amdgcn_mfma_f32_16x16x16bf16_1k(
                              vB[ks * 2], pfB[qs][ks], accO[qs][0], 0, 0, 0);
            accO[qs][1] = __builtin_amdgcn_mfma_f32_16x16x16bf16_1k(
                              vB[ks * 2 + 1], pfB[qs][ks], accO[qs][1], 0, 0, 0);
            accS[qs]    = __builtin_amdgcn_mfma_f32_16x16x16bf16_1k(
                              ones4, pfB[qs][ks], accS[qs], 0, 0, 0);
        }
    }
#undef TILE

    // ---- epilogue ----
#pragma unroll
    for (int qs = 0; qs < 2; ++qs) {
        float inv = 1.0f / accS[qs][0];
        int s = woff + qs * 16 + l15;
        float* op = out + ((size_t)b * 1024 + s) * 256 + h * 32;
#pragma unroll
        for (int dvs = 0; dvs < 2; ++dvs) {
            float4 o4 = make_float4(accO[qs][dvs][0] * inv, accO[qs][dvs][1] * inv,
                                    accO[qs][dvs][2] * inv, accO[qs][dvs][3] * inv);
            *(float4*)&op[dvs * 16 + quad * 4] = o4;
        }
    }
}

// ---------------------------------------------------------------------------
extern "C" void kernel_launch(void* const* d_in, const int* in_sizes, int n_in,
                              void* d_out, int out_size, void* d_ws, size_t ws_size,
                              hipStream_t stream)
{
    const float* query = (const float*)d_in[0];
    const float* key   = (const float*)d_in[1];
    const float* value = (const float*)d_in[2];
    const float* mask  = (const float*)d_in[3];
    const float* Wq    = (const float*)d_in[4];
    const float* Wk    = (const float*)d_in[5];
    const float* Wv    = (const float*)d_in[6];
    float* out = (float*)d_out;

    const size_t per = (size_t)B_ * H_ * S_ * DK_;
    short* qpH = (short*)d_ws;
    short* qpL = qpH + per;
    short* kpH = qpL + per;
    short* kpL = kpH + per;
    short* vpT = kpL + per;
    short* WpH = vpT + per;
    short* WpL = WpH + 3 * 256 * 256;

    prep_w<<<dim3(24, 4), 256, 0, stream>>>(Wq, Wk, Wv, WpH, WpL);
    proj_kernel<<<dim3(512, 3), 256, 0, stream>>>(query, key, value, mask, WpH, WpL,
                                                  qpH, qpL, kpH, kpL, vpT);
    attn_kernel<<<dim3(8, H_, B_), 256, 0, stream>>>(qpH, qpL, kpH, kpL, vpT, out);
}

// Round 7
// 265.179 us; speedup vs baseline: 1.0716x; 1.0255x over previous
//
#include <hip/hip_runtime.h>
#include <math.h>

#define B_  32
#define S_  1024
#define D_  256
#define H_  8
#define DK_ 32
#define MASKV (-1e-30f)
#define LOG2E 1.44269504f

typedef __attribute__((ext_vector_type(4))) short bf4_t;   // 4 bf16 (2 VGPRs)
typedef __attribute__((ext_vector_type(8))) short bf8_t;   // 8 bf16 (4 VGPRs)
typedef __attribute__((ext_vector_type(4))) float f4_t;    // MFMA accumulator

__device__ __forceinline__ unsigned fbits(float x) {
    union { float f; unsigned u; } v; v.f = x; return v.u;
}
__device__ __forceinline__ float bitsf(unsigned u) {
    union { unsigned u; float f; } v; v.u = u; return v.f;
}

#if __has_builtin(__builtin_amdgcn_exp2f)
#define EXP2F(x) __builtin_amdgcn_exp2f(x)
#else
#define EXP2F(x) __expf((x) * 0.69314718f)
#endif

__device__ __forceinline__ void gld16(const void* g, void* l) {
    __builtin_amdgcn_global_load_lds(
        (const __attribute__((address_space(1))) void*)g,
        (__attribute__((address_space(3))) void*)l, 16, 0, 0);
}

// v_perm selector: D = [S1.hi16 (low half), S0.hi16 (high half)]
#define PSEL 0x07060302u

// ===========================================================================
// FRAG-PACKED LAYOUTS (lane-linear):
//  W  (per a): off = a*65536 + ((kc*16 + ng)*64 + lane)*8 + j
//  Q/K (per bh): off = ((bh*64 + grp)*64 + lane)*8 + j
//  A wave's MFMA fragment load = 64 lanes x 16B = 1KB contiguous.
// ===========================================================================

// ---------------------------------------------------------------------------
// prep_w: W[h][d][k] fp32 -> frag-packed hi/lo bf16.  (byte-identical to r6)
// ---------------------------------------------------------------------------
__global__ __launch_bounds__(256) void prep_w(
    const float* __restrict__ Wq, const float* __restrict__ Wk,
    const float* __restrict__ Wv, short* __restrict__ WpH, short* __restrict__ WpL)
{
    const int a = blockIdx.x >> 3;
    const int h = blockIdx.x & 7;
    const float* W = (a == 0 ? Wq : (a == 1 ? Wk : Wv)) + (size_t)h * 256 * 32;
    const int t = threadIdx.x;
    const int k    = t & 31;
    const int dgrp = t >> 5;
    const int ng   = h * 2 + (k >> 4);
    const int l15  = k & 15;
#pragma unroll
    for (int jj = blockIdx.y * 2; jj < blockIdx.y * 2 + 2; ++jj) {
        const int d0 = jj * 32 + dgrp * 4;
        float x[4];
#pragma unroll
        for (int r = 0; r < 4; ++r) x[r] = W[(size_t)(d0 + r) * 32 + k];
        unsigned hu[4], lu[4];
#pragma unroll
        for (int r = 0; r < 4; ++r) {
            unsigned hb = (fbits(x[r]) + 0x8000u) & 0xFFFF0000u;
            hu[r] = hb;
            lu[r] = fbits(x[r] - bitsf(hb)) + 0x8000u;
        }
        uint2 hp = make_uint2(__builtin_amdgcn_perm(hu[1], hu[0], PSEL),
                              __builtin_amdgcn_perm(hu[3], hu[2], PSEL));
        uint2 lp = make_uint2(__builtin_amdgcn_perm(lu[1], lu[0], PSEL),
                              __builtin_amdgcn_perm(lu[3], lu[2], PSEL));
        const int quad = (d0 >> 3) & 3;
        const int jb   = d0 & 7;
        size_t off = (size_t)a * 65536
                   + ((size_t)(jj * 16 + ng) * 64 + quad * 16 + l15) * 8 + jb;
        *(uint2*)&WpH[off] = hp;
        *(uint2*)&WpL[off] = lp;
    }
}

// ---------------------------------------------------------------------------
// proj: C[32768,256] = X * Wt^T via split-bf16 MFMA.
// DEPTH-2 REGISTER PIPELINE on W: while kc computes from buffer A, the W
// fragments of kc+1 load from global into buffer B (static names, fully
// unrolled schedule) -> every W load is covered by 48 MFMAs of compute,
// removing the per-kc exposed L2 latency that made r6 proj latency-bound
// (MfmaUtil 16%, VALUBusy 14%, all idle). W addresses are base + constant
// offsets. X staged to LDS in two kc-halves (32 KB); 3 barriers total.
// ---------------------------------------------------------------------------
__global__ __launch_bounds__(256) void proj_kernel(
    const float* __restrict__ Xq, const float* __restrict__ Xk,
    const float* __restrict__ Xv, const float* __restrict__ mask,
    const short* __restrict__ WpH, const short* __restrict__ WpL,
    short* __restrict__ qpH, short* __restrict__ qpL,
    short* __restrict__ kpH, short* __restrict__ kpL,
    short* __restrict__ vpT)
{
    __shared__ __align__(16) short XsH[8192];   // 4 kc x 4 t x 64 lanes x 8
    __shared__ __align__(16) short XsL[8192];

    const int a  = blockIdx.y;
    const float* X = (a == 0 ? Xq : (a == 1 ? Xk : Xv));
    const short* WH = WpH + (size_t)a * 65536;
    const short* WL = WpL + (size_t)a * 65536;
    const int m0 = blockIdx.x * 64;

    const int tid  = threadIdx.x;
    const int lane = tid & 63;
    const int wv   = tid >> 6;
    const int l15  = lane & 15;
    const int quad = lane >> 4;

    f4_t acc[4][4];
#pragma unroll
    for (int i = 0; i < 4; ++i)
#pragma unroll
        for (int j = 0; j < 4; ++j) acc[i][j] = (f4_t){0.f, 0.f, 0.f, 0.f};

    const int r    = tid >> 2;               // row 0..63
    const int dseg = tid & 3;                // local kc
    const int tix  = r >> 4;
    const int rl15 = r & 15;

    // per-wave W fragment base (shorts); per-(kc,ns) offsets are constants
    const short* WHb = WH + (wv * 4) * 512 + lane * 8;
    const short* WLb = WL + (wv * 4) * 512 + lane * 8;

    bf8_t wAh[4], wAl[4], wBh[4], wBl[4];

#define WLOAD(BUFh, BUFl, KC)                                                  \
    _Pragma("unroll")                                                          \
    for (int ns = 0; ns < 4; ++ns) {                                           \
        BUFh[ns] = *(const bf8_t*)&WHb[(KC) * 8192 + ns * 512];                \
        BUFl[ns] = *(const bf8_t*)&WLb[(KC) * 8192 + ns * 512];                \
    }

#define STAGE_X(H2)                                                            \
    {                                                                          \
        const float* xp = X + (size_t)(m0 + r) * 256 + (H2) * 128 + dseg * 32; \
        _Pragma("unroll")                                                      \
        for (int q = 0; q < 4; ++q) {                                          \
            float4 x0 = *(const float4*)(xp + q * 8);                          \
            float4 x1 = *(const float4*)(xp + q * 8 + 4);                      \
            float xv[8] = {x0.x, x0.y, x0.z, x0.w, x1.x, x1.y, x1.z, x1.w};    \
            bf8_t hi, lo;                                                      \
            _Pragma("unroll")                                                  \
            for (int j = 0; j < 8; ++j) {                                      \
                unsigned hu = (fbits(xv[j]) + 0x8000u) & 0xFFFF0000u;          \
                hi[j] = (short)(hu >> 16);                                     \
                lo[j] = (short)((fbits(xv[j] - bitsf(hu)) + 0x8000u) >> 16);   \
            }                                                                  \
            const int off = ((dseg * 4 + tix) * 64 + q * 16 + rl15) * 8;       \
            *(bf8_t*)&XsH[off] = hi;                                           \
            *(bf8_t*)&XsL[off] = lo;                                           \
        }                                                                      \
    }

#define COMPUTE(KCL, BUFh, BUFl)                                               \
    {                                                                          \
        bf8_t xH[4], xL[4];                                                    \
        _Pragma("unroll")                                                      \
        for (int t = 0; t < 4; ++t) {                                          \
            xH[t] = *(const bf8_t*)&XsH[(((KCL) * 4 + t) * 64 + lane) * 8];    \
            xL[t] = *(const bf8_t*)&XsL[(((KCL) * 4 + t) * 64 + lane) * 8];    \
        }                                                                      \
        _Pragma("unroll")                                                      \
        for (int ns = 0; ns < 4; ++ns) {                                       \
            _Pragma("unroll")                                                  \
            for (int t = 0; t < 4; ++t) {                                      \
                f4_t c = acc[t][ns];                                           \
                if (a < 2) {                                                   \
                    c = __builtin_amdgcn_mfma_f32_16x16x32_bf16(BUFh[ns], xH[t], c, 0, 0, 0); \
                    c = __builtin_amdgcn_mfma_f32_16x16x32_bf16(BUFl[ns], xH[t], c, 0, 0, 0); \
                    c = __builtin_amdgcn_mfma_f32_16x16x32_bf16(BUFh[ns], xL[t], c, 0, 0, 0); \
                } else {                                                       \
                    c = __builtin_amdgcn_mfma_f32_16x16x32_bf16(xH[t], BUFh[ns], c, 0, 0, 0); \
                    c = __builtin_amdgcn_mfma_f32_16x16x32_bf16(xH[t], BUFl[ns], c, 0, 0, 0); \
                    c = __builtin_amdgcn_mfma_f32_16x16x32_bf16(xL[t], BUFh[ns], c, 0, 0, 0); \
                }                                                              \
                acc[t][ns] = c;                                                \
            }                                                                  \
        }                                                                      \
    }

    WLOAD(wAh, wAl, 0)                 // kc0 W in flight during X staging
    STAGE_X(0)
    __syncthreads();

    WLOAD(wBh, wBl, 1)  COMPUTE(0, wAh, wAl)
    WLOAD(wAh, wAl, 2)  COMPUTE(1, wBh, wBl)
    WLOAD(wBh, wBl, 3)  COMPUTE(2, wAh, wAl)
    WLOAD(wAh, wAl, 4)  COMPUTE(3, wBh, wBl)

    __syncthreads();                   // half-0 LDS reads done
    STAGE_X(1)
    __syncthreads();

    WLOAD(wBh, wBl, 5)  COMPUTE(0, wAh, wAl)
    WLOAD(wAh, wAl, 6)  COMPUTE(1, wBh, wBl)
    WLOAD(wBh, wBl, 7)  COMPUTE(2, wAh, wAl)
                        COMPUTE(3, wBh, wBl)

#undef WLOAD
#undef STAGE_X
#undef COMPUTE

    // ---- epilogue ----
    const int b  = m0 >> 10;
    const int sB = m0 & 1023;
    if (a < 2) {
        short* dH = (a == 0) ? qpH : kpH;
        short* dL = (a == 0) ? qpL : kpL;
        const float* mbp = mask + (size_t)b * 1024;
#pragma unroll
        for (int t = 0; t < 4; ++t) {
            const int s = sB + t * 16 + l15;
            const float scale = (a == 0) ? LOG2E : mbp[s];
            const int grp = (sB >> 4) + t;
#pragma unroll
            for (int ns = 0; ns < 4; ++ns) {
                const int h_    = wv * 2 + (ns >> 1);
                const int quadA = (ns & 1) * 2 + (quad >> 1);
                const int jb    = (quad & 1) * 4;
                unsigned hu[4], lu[4];
#pragma unroll
                for (int rr = 0; rr < 4; ++rr) {
                    float x = acc[t][ns][rr] * scale;
                    unsigned h32 = fbits(x) + 0x8000u;
                    hu[rr] = h32;
                    float hf = bitsf(h32 & 0xFFFF0000u);
                    lu[rr] = fbits(x - hf) + 0x8000u;
                }
                uint2 hp = make_uint2(__builtin_amdgcn_perm(hu[1], hu[0], PSEL),
                                      __builtin_amdgcn_perm(hu[3], hu[2], PSEL));
                uint2 lp = make_uint2(__builtin_amdgcn_perm(lu[1], lu[0], PSEL),
                                      __builtin_amdgcn_perm(lu[3], lu[2], PSEL));
                size_t off = (((size_t)(b * 8 + h_) * 64 + grp) * 64
                              + quadA * 16 + l15) * 8 + jb;
                *(uint2*)&dH[off] = hp;
                *(uint2*)&dL[off] = lp;
            }
        }
    } else {
#pragma unroll
        for (int t = 0; t < 4; ++t) {
            int sr = sB + t * 16 + quad * 4;
#pragma unroll
            for (int ns = 0; ns < 4; ++ns) {
                int n = wv * 64 + ns * 16 + l15;
                int h = n >> 5, k = n & 31;
                unsigned eu[4];
#pragma unroll
                for (int rr = 0; rr < 4; ++rr) eu[rr] = fbits(acc[t][ns][rr]) + 0x8000u;
                uint2 pk = make_uint2(__builtin_amdgcn_perm(eu[1], eu[0], PSEL),
                                      __builtin_amdgcn_perm(eu[3], eu[2], PSEL));
                *(uint2*)&vpT[((size_t)(b * 8 + h) * 32 + k) * 1024 + sr] = pk;
            }
        }
    }
}

// ---------------------------------------------------------------------------
// attn: r6 cross-kt software pipeline, unchanged except the P->bf16 pack
// TRUNCATES instead of rounds (drops 64 v_add/kt/lane, ~18% of VALU).
// Safe: P err <= 2^-8 one-sided and the same truncated P feeds both PV and
// the ones-MFMA denominator, so the bias cancels in O = sum(PV)/sum(P).
// ---------------------------------------------------------------------------
__global__ __launch_bounds__(256) void attn_kernel(
    const short* __restrict__ qpH, const short* __restrict__ qpL,
    const short* __restrict__ kpH, const short* __restrict__ kpL,
    const short* __restrict__ vpT, float* __restrict__ out)
{
    __shared__ __align__(16) short KsH[2][2048];   // kt-tile: 4 ks x 64 lanes x 8
    __shared__ __align__(16) short KsL[2][2048];
    __shared__ __align__(16) short VsT[2][32 * 72];

    const int tid  = threadIdx.x;
    const int lane = tid & 63;
    const int wv   = tid >> 6;
    const int l15  = lane & 15;
    const int quad = lane >> 4;

    // launch-linear id -> XCD-contiguous (bh, qt) assignment
    const int L  = (blockIdx.z * gridDim.y + blockIdx.y) * gridDim.x + blockIdx.x;
    const int li = L >> 3;
    const int bh = (L & 7) * 32 + (li >> 3);
    const int qt = li & 7;
    const int b  = bh >> 3;
    const int h  = bh & 7;
    const int woff = qt * 128 + wv * 32;

    bf8_t qh[2], ql[2];
#pragma unroll
    for (int qs = 0; qs < 2; ++qs) {
        const int grp = qt * 8 + wv * 2 + qs;      // (woff + qs*16) >> 4
        size_t off = (((size_t)bh * 64 + grp) * 64 + lane) * 8;
        qh[qs] = *(const bf8_t*)&qpH[off];
        ql[qs] = *(const bf8_t*)&qpL[off];
    }

    f4_t accO[2][2];
    f4_t accS[2];
#pragma unroll
    for (int i = 0; i < 2; ++i) {
        accS[i] = (f4_t){0.f, 0.f, 0.f, 0.f};
#pragma unroll
        for (int j = 0; j < 2; ++j) accO[i][j] = (f4_t){0.f, 0.f, 0.f, 0.f};
    }
    const bf4_t ones4 = {(short)0x3F80, (short)0x3F80, (short)0x3F80, (short)0x3F80};

    const int dv = tid >> 3, seg = tid & 7;

    bf4_t vA[8], vB[8];
    bf4_t pfA[2][4], pfB[2][4];

// one pipelined k-tile. KT: tile index; CUR: its LDS buffer (== KT&1);
// DO_STAGE: stage tile KT+1; DO_PV: run PV for tile KT-1 from VIN/PIN.
#define TILE(KT, CUR, DO_STAGE, DO_PV, VIN, VOUT, PIN, POUT)                    \
    {                                                                           \
        /* 1. V(KT) frags LDS -> VOUT regs (consumed next tile) */              \
        _Pragma("unroll")                                                       \
        for (int ks = 0; ks < 4; ++ks) {                                        \
            VOUT[ks * 2]     = *(const bf4_t*)&VsT[CUR][l15 * 72 + ks * 16 + quad * 4];       \
            VOUT[ks * 2 + 1] = *(const bf4_t*)&VsT[CUR][(16 + l15) * 72 + ks * 16 + quad * 4];\
        }                                                                       \
        /* 2. issue staging of tile KT+1 into buf CUR^1 (no wait) */            \
        uint4 vreg;                                                             \
        if (DO_STAGE) {                                                         \
            size_t toff = ((size_t)bh * 64 + (size_t)((KT) + 1) * 4) * 512;     \
            gld16(kpH + toff + wv * 512 + lane * 8, (char*)KsH[(CUR) ^ 1] + wv * 1024); \
            gld16(kpL + toff + wv * 512 + lane * 8, (char*)KsL[(CUR) ^ 1] + wv * 1024); \
            vreg = *(const uint4*)&vpT[((size_t)bh * 32 + dv) * 1024            \
                                       + (size_t)((KT) + 1) * 64 + seg * 8];    \
        }                                                                       \
        __builtin_amdgcn_s_setprio(1);                                          \
        /* 3. fused per-ks: QK(KT) -> PV(KT-1) -> exp/pack(KT) */               \
        _Pragma("unroll")                                                       \
        for (int ks = 0; ks < 4; ++ks) {                                        \
            bf8_t kh = *(const bf8_t*)&KsH[CUR][ks * 512 + lane * 8];           \
            bf8_t kl = *(const bf8_t*)&KsL[CUR][ks * 512 + lane * 8];           \
            f4_t sc[2];                                                         \
            _Pragma("unroll")                                                   \
            for (int qs = 0; qs < 2; ++qs) {                                    \
                f4_t c = __builtin_amdgcn_mfma_f32_16x16x32_bf16(kh, qh[qs],    \
                             (f4_t){0.f, 0.f, 0.f, 0.f}, 0, 0, 0);              \
                c = __builtin_amdgcn_mfma_f32_16x16x32_bf16(kl, qh[qs], c, 0, 0, 0); \
                c = __builtin_amdgcn_mfma_f32_16x16x32_bf16(kh, ql[qs], c, 0, 0, 0); \
                sc[qs] = c;                                                     \
            }                                                                   \
            if (DO_PV) {                                                        \
                _Pragma("unroll")                                               \
                for (int qs = 0; qs < 2; ++qs) {                                \
                    accO[qs][0] = __builtin_amdgcn_mfma_f32_16x16x16bf16_1k(    \
                                      VIN[ks * 2], PIN[qs][ks], accO[qs][0], 0, 0, 0);     \
                    accO[qs][1] = __builtin_amdgcn_mfma_f32_16x16x16bf16_1k(    \
                                      VIN[ks * 2 + 1], PIN[qs][ks], accO[qs][1], 0, 0, 0); \
                    accS[qs]    = __builtin_amdgcn_mfma_f32_16x16x16bf16_1k(    \
                                      ones4, PIN[qs][ks], accS[qs], 0, 0, 0);   \
                }                                                               \
            }                                                                   \
            _Pragma("unroll")                                                   \
            for (int qs = 0; qs < 2; ++qs) {                                    \
                unsigned eu[4];                                                 \
                _Pragma("unroll")                                               \
                for (int r = 0; r < 4; ++r)                                     \
                    eu[r] = fbits(EXP2F(sc[qs][r]));     /* truncate to bf16 */ \
                union { uint2 u; bf4_t v; } cv;                                 \
                cv.u = make_uint2(__builtin_amdgcn_perm(eu[1], eu[0], PSEL),    \
                                  __builtin_amdgcn_perm(eu[3], eu[2], PSEL));   \
                POUT[qs][ks] = cv.v;                                            \
            }                                                                   \
        }                                                                       \
        __builtin_amdgcn_s_setprio(0);                                          \
        /* 4. deferred V write for tile KT+1 (vmcnt wait lands here) */         \
        if (DO_STAGE) *(uint4*)&VsT[(CUR) ^ 1][dv * 72 + seg * 8] = vreg;       \
        __syncthreads();                                                        \
    }

    // ---- prologue: stage tile 0 -> buf 0 (linear frag-packed copy) ----
    {
        size_t toff = ((size_t)bh * 64) * 512;     // kt = 0
        gld16(kpH + toff + wv * 512 + lane * 8, (char*)KsH[0] + wv * 1024);
        gld16(kpL + toff + wv * 512 + lane * 8, (char*)KsL[0] + wv * 1024);
        uint4 v0 = *(const uint4*)&vpT[((size_t)bh * 32 + dv) * 1024 + seg * 8];
        *(uint4*)&VsT[0][dv * 72 + seg * 8] = v0;
    }
    __syncthreads();

    TILE(0, 0, 1, 0, vA, vA, pfA, pfA)            // fills vA = V(0), pfA = P(0)
    for (int i = 0; i < 7; ++i) {
        TILE(2 * i + 1, 1, 1, 1, vA, vB, pfA, pfB)   // PV(2i),   fills V/P(2i+1)
        TILE(2 * i + 2, 0, 1, 1, vB, vA, pfB, pfA)   // PV(2i+1), fills V/P(2i+2)
    }
    TILE(15, 1, 0, 1, vA, vB, pfA, pfB)           // PV(14), fills vB = V(15), pfB = P(15)

    // ---- drain: PV for tile 15 ----
#pragma unroll
    for (int ks = 0; ks < 4; ++ks) {
#pragma unroll
        for (int qs = 0; qs < 2; ++qs) {
            accO[qs][0] = __builtin_amdgcn_mfma_f32_16x16x16bf16_1k(
                              vB[ks * 2], pfB[qs][ks], accO[qs][0], 0, 0, 0);
            accO[qs][1] = __builtin_amdgcn_mfma_f32_16x16x16bf16_1k(
                              vB[ks * 2 + 1], pfB[qs][ks], accO[qs][1], 0, 0, 0);
            accS[qs]    = __builtin_amdgcn_mfma_f32_16x16x16bf16_1k(
                              ones4, pfB[qs][ks], accS[qs], 0, 0, 0);
        }
    }
#undef TILE

    // ---- epilogue ----
#pragma unroll
    for (int qs = 0; qs < 2; ++qs) {
        float inv = 1.0f / accS[qs][0];
        int s = woff + qs * 16 + l15;
        float* op = out + ((size_t)b * 1024 + s) * 256 + h * 32;
#pragma unroll
        for (int dvs = 0; dvs < 2; ++dvs) {
            float4 o4 = make_float4(accO[qs][dvs][0] * inv, accO[qs][dvs][1] * inv,
                                    accO[qs][dvs][2] * inv, accO[qs][dvs][3] * inv);
            *(float4*)&op[dvs * 16 + quad * 4] = o4;
        }
    }
}

// ---------------------------------------------------------------------------
extern "C" void kernel_launch(void* const* d_in, const int* in_sizes, int n_in,
                              void* d_out, int out_size, void* d_ws, size_t ws_size,
                              hipStream_t stream)
{
    const float* query = (const float*)d_in[0];
    const float* key   = (const float*)d_in[1];
    const float* value = (const float*)d_in[2];
    const float* mask  = (const float*)d_in[3];
    const float* Wq    = (const float*)d_in[4];
    const float* Wk    = (const float*)d_in[5];
    const float* Wv    = (const float*)d_in[6];
    float* out = (float*)d_out;

    const size_t per = (size_t)B_ * H_ * S_ * DK_;
    short* qpH = (short*)d_ws;
    short* qpL = qpH + per;
    short* kpH = qpL + per;
    short* kpL = kpH + per;
    short* vpT = kpL + per;
    short* WpH = vpT + per;
    short* WpL = WpH + 3 * 256 * 256;

    prep_w<<<dim3(24, 4), 256, 0, stream>>>(Wq, Wk, Wv, WpH, WpL);
    proj_kernel<<<dim3(512, 3), 256, 0, stream>>>(query, key, value, mask, WpH, WpL,
                                                  qpH, qpL, kpH, kpL, vpT);
    attn_kernel<<<dim3(8, H_, B_), 256, 0, stream>>>(qpH, qpL, kpH, kpL, vpT, out);
}

// Round 8
// 257.795 us; speedup vs baseline: 1.1023x; 1.0286x over previous
//
#include <hip/hip_runtime.h>
#include <math.h>

#define B_  32
#define S_  1024
#define D_  256
#define H_  8
#define DK_ 32
#define MASKV (-1e-30f)
#define LOG2E 1.44269504f

typedef __attribute__((ext_vector_type(4))) short bf4_t;   // 4 bf16 (2 VGPRs)
typedef __attribute__((ext_vector_type(8))) short bf8_t;   // 8 bf16 (4 VGPRs)
typedef __attribute__((ext_vector_type(4))) float f4_t;    // MFMA accumulator

__device__ __forceinline__ unsigned fbits(float x) {
    union { float f; unsigned u; } v; v.f = x; return v.u;
}
__device__ __forceinline__ float bitsf(unsigned u) {
    union { unsigned u; float f; } v; v.u = u; return v.f;
}

#if __has_builtin(__builtin_amdgcn_exp2f)
#define EXP2F(x) __builtin_amdgcn_exp2f(x)
#else
#define EXP2F(x) __expf((x) * 0.69314718f)
#endif

// v_perm selector: D = [S1.hi16 (low half), S0.hi16 (high half)]
#define PSEL 0x07060302u

// ===========================================================================
// FRAG-PACKED LAYOUTS (lane-linear, wave-contiguous):
//  W   (per a): off = a*65536 + ((kc*16 + ng)*64 + lane)*8 + j
//  Q/K (per bh): off = ((bh*64 + grp)*64 + lane)*8 + j
//  V   (per bh): off = bh*32768 + (((kt*4 + ks)*2 + p)*256) + lane*4 + j
//      holds V[dv = p*16 + (lane&15)][key = kt*64 + ks*16 + (lane>>4)*4 + j]
//  Every MFMA fragment load = 64 lanes x 8-16B contiguous.
// ===========================================================================

// ---------------------------------------------------------------------------
// prep_w: W[h][d][k] fp32 -> frag-packed hi/lo bf16.  (byte-identical to r7)
// ---------------------------------------------------------------------------
__global__ __launch_bounds__(256) void prep_w(
    const float* __restrict__ Wq, const float* __restrict__ Wk,
    const float* __restrict__ Wv, short* __restrict__ WpH, short* __restrict__ WpL)
{
    const int a = blockIdx.x >> 3;
    const int h = blockIdx.x & 7;
    const float* W = (a == 0 ? Wq : (a == 1 ? Wk : Wv)) + (size_t)h * 256 * 32;
    const int t = threadIdx.x;
    const int k    = t & 31;
    const int dgrp = t >> 5;
    const int ng   = h * 2 + (k >> 4);
    const int l15  = k & 15;
#pragma unroll
    for (int jj = blockIdx.y * 2; jj < blockIdx.y * 2 + 2; ++jj) {
        const int d0 = jj * 32 + dgrp * 4;
        float x[4];
#pragma unroll
        for (int r = 0; r < 4; ++r) x[r] = W[(size_t)(d0 + r) * 32 + k];
        unsigned hu[4], lu[4];
#pragma unroll
        for (int r = 0; r < 4; ++r) {
            unsigned hb = (fbits(x[r]) + 0x8000u) & 0xFFFF0000u;
            hu[r] = hb;
            lu[r] = fbits(x[r] - bitsf(hb)) + 0x8000u;
        }
        uint2 hp = make_uint2(__builtin_amdgcn_perm(hu[1], hu[0], PSEL),
                              __builtin_amdgcn_perm(hu[3], hu[2], PSEL));
        uint2 lp = make_uint2(__builtin_amdgcn_perm(lu[1], lu[0], PSEL),
                              __builtin_amdgcn_perm(lu[3], lu[2], PSEL));
        const int quad = (d0 >> 3) & 3;
        const int jb   = d0 & 7;
        size_t off = (size_t)a * 65536
                   + ((size_t)(jj * 16 + ng) * 64 + quad * 16 + l15) * 8 + jb;
        *(uint2*)&WpH[off] = hp;
        *(uint2*)&WpL[off] = lp;
    }
}

// ---------------------------------------------------------------------------
// proj: C[32768,256] = X * Wt^T via split-bf16 MFMA.  (r7 structure; only
// the a==2 (V) epilogue changes: stores frag-packed vpF so attn can load V
// fragments as 512B wave-contiguous chunks. Same lane->element mapping,
// same 8B coalesced stores, different address function.)
// ---------------------------------------------------------------------------
__global__ __launch_bounds__(256) void proj_kernel(
    const float* __restrict__ Xq, const float* __restrict__ Xk,
    const float* __restrict__ Xv, const float* __restrict__ mask,
    const short* __restrict__ WpH, const short* __restrict__ WpL,
    short* __restrict__ qpH, short* __restrict__ qpL,
    short* __restrict__ kpH, short* __restrict__ kpL,
    short* __restrict__ vpF)
{
    __shared__ __align__(16) short XsH[8192];   // 4 kc x 4 t x 64 lanes x 8
    __shared__ __align__(16) short XsL[8192];

    const int a  = blockIdx.y;
    const float* X = (a == 0 ? Xq : (a == 1 ? Xk : Xv));
    const short* WH = WpH + (size_t)a * 65536;
    const short* WL = WpL + (size_t)a * 65536;
    const int m0 = blockIdx.x * 64;

    const int tid  = threadIdx.x;
    const int lane = tid & 63;
    const int wv   = tid >> 6;
    const int l15  = lane & 15;
    const int quad = lane >> 4;

    f4_t acc[4][4];
#pragma unroll
    for (int i = 0; i < 4; ++i)
#pragma unroll
        for (int j = 0; j < 4; ++j) acc[i][j] = (f4_t){0.f, 0.f, 0.f, 0.f};

    const int r    = tid >> 2;               // row 0..63
    const int dseg = tid & 3;                // local kc
    const int tix  = r >> 4;
    const int rl15 = r & 15;

    // per-wave W fragment base (shorts); per-(kc,ns) offsets are constants
    const short* WHb = WH + (wv * 4) * 512 + lane * 8;
    const short* WLb = WL + (wv * 4) * 512 + lane * 8;

    bf8_t wAh[4], wAl[4], wBh[4], wBl[4];

#define WLOAD(BUFh, BUFl, KC)                                                  \
    _Pragma("unroll")                                                          \
    for (int ns = 0; ns < 4; ++ns) {                                           \
        BUFh[ns] = *(const bf8_t*)&WHb[(KC) * 8192 + ns * 512];                \
        BUFl[ns] = *(const bf8_t*)&WLb[(KC) * 8192 + ns * 512];                \
    }

#define STAGE_X(H2)                                                            \
    {                                                                          \
        const float* xp = X + (size_t)(m0 + r) * 256 + (H2) * 128 + dseg * 32; \
        _Pragma("unroll")                                                      \
        for (int q = 0; q < 4; ++q) {                                          \
            float4 x0 = *(const float4*)(xp + q * 8);                          \
            float4 x1 = *(const float4*)(xp + q * 8 + 4);                      \
            float xv[8] = {x0.x, x0.y, x0.z, x0.w, x1.x, x1.y, x1.z, x1.w};    \
            bf8_t hi, lo;                                                      \
            _Pragma("unroll")                                                  \
            for (int j = 0; j < 8; ++j) {                                      \
                unsigned hu = (fbits(xv[j]) + 0x8000u) & 0xFFFF0000u;          \
                hi[j] = (short)(hu >> 16);                                     \
                lo[j] = (short)((fbits(xv[j] - bitsf(hu)) + 0x8000u) >> 16);   \
            }                                                                  \
            const int off = ((dseg * 4 + tix) * 64 + q * 16 + rl15) * 8;       \
            *(bf8_t*)&XsH[off] = hi;                                           \
            *(bf8_t*)&XsL[off] = lo;                                           \
        }                                                                      \
    }

#define COMPUTE(KCL, BUFh, BUFl)                                               \
    {                                                                          \
        bf8_t xH[4], xL[4];                                                    \
        _Pragma("unroll")                                                      \
        for (int t = 0; t < 4; ++t) {                                          \
            xH[t] = *(const bf8_t*)&XsH[(((KCL) * 4 + t) * 64 + lane) * 8];    \
            xL[t] = *(const bf8_t*)&XsL[(((KCL) * 4 + t) * 64 + lane) * 8];    \
        }                                                                      \
        _Pragma("unroll")                                                      \
        for (int ns = 0; ns < 4; ++ns) {                                       \
            _Pragma("unroll")                                                  \
            for (int t = 0; t < 4; ++t) {                                      \
                f4_t c = acc[t][ns];                                           \
                if (a < 2) {                                                   \
                    c = __builtin_amdgcn_mfma_f32_16x16x32_bf16(BUFh[ns], xH[t], c, 0, 0, 0); \
                    c = __builtin_amdgcn_mfma_f32_16x16x32_bf16(BUFl[ns], xH[t], c, 0, 0, 0); \
                    c = __builtin_amdgcn_mfma_f32_16x16x32_bf16(BUFh[ns], xL[t], c, 0, 0, 0); \
                } else {                                                       \
                    c = __builtin_amdgcn_mfma_f32_16x16x32_bf16(xH[t], BUFh[ns], c, 0, 0, 0); \
                    c = __builtin_amdgcn_mfma_f32_16x16x32_bf16(xH[t], BUFl[ns], c, 0, 0, 0); \
                    c = __builtin_amdgcn_mfma_f32_16x16x32_bf16(xL[t], BUFh[ns], c, 0, 0, 0); \
                }                                                              \
                acc[t][ns] = c;                                                \
            }                                                                  \
        }                                                                      \
    }

    WLOAD(wAh, wAl, 0)                 // kc0 W in flight during X staging
    STAGE_X(0)
    __syncthreads();

    WLOAD(wBh, wBl, 1)  COMPUTE(0, wAh, wAl)
    WLOAD(wAh, wAl, 2)  COMPUTE(1, wBh, wBl)
    WLOAD(wBh, wBl, 3)  COMPUTE(2, wAh, wAl)
    WLOAD(wAh, wAl, 4)  COMPUTE(3, wBh, wBl)

    __syncthreads();                   // half-0 LDS reads done
    STAGE_X(1)
    __syncthreads();

    WLOAD(wBh, wBl, 5)  COMPUTE(0, wAh, wAl)
    WLOAD(wAh, wAl, 6)  COMPUTE(1, wBh, wBl)
    WLOAD(wBh, wBl, 7)  COMPUTE(2, wAh, wAl)
                        COMPUTE(3, wBh, wBl)

#undef WLOAD
#undef STAGE_X
#undef COMPUTE

    // ---- epilogue ----
    const int b  = m0 >> 10;
    const int sB = m0 & 1023;
    if (a < 2) {
        short* dH = (a == 0) ? qpH : kpH;
        short* dL = (a == 0) ? qpL : kpL;
        const float* mbp = mask + (size_t)b * 1024;
#pragma unroll
        for (int t = 0; t < 4; ++t) {
            const int s = sB + t * 16 + l15;
            const float scale = (a == 0) ? LOG2E : mbp[s];
            const int grp = (sB >> 4) + t;
#pragma unroll
            for (int ns = 0; ns < 4; ++ns) {
                const int h_    = wv * 2 + (ns >> 1);
                const int quadA = (ns & 1) * 2 + (quad >> 1);
                const int jb    = (quad & 1) * 4;
                unsigned hu[4], lu[4];
#pragma unroll
                for (int rr = 0; rr < 4; ++rr) {
                    float x = acc[t][ns][rr] * scale;
                    unsigned h32 = fbits(x) + 0x8000u;
                    hu[rr] = h32;
                    float hf = bitsf(h32 & 0xFFFF0000u);
                    lu[rr] = fbits(x - hf) + 0x8000u;
                }
                uint2 hp = make_uint2(__builtin_amdgcn_perm(hu[1], hu[0], PSEL),
                                      __builtin_amdgcn_perm(hu[3], hu[2], PSEL));
                uint2 lp = make_uint2(__builtin_amdgcn_perm(lu[1], lu[0], PSEL),
                                      __builtin_amdgcn_perm(lu[3], lu[2], PSEL));
                size_t off = (((size_t)(b * 8 + h_) * 64 + grp) * 64
                              + quadA * 16 + l15) * 8 + jb;
                *(uint2*)&dH[off] = hp;
                *(uint2*)&dL[off] = lp;
            }
        }
    } else {
        // V epilogue -> frag-packed vpF.
        // lane (l15,quad) holds V[key = sB + t*16 + quad*4 + rr][dv = (ns&1)*16 + l15]
        // target: (((bh*16+kt)*4+ks)*2+p)*256 + (quad*16+l15)*4 + rr,
        // kt = sB>>6, ks = t, p = ns&1, bh = b*8 + wv*2 + (ns>>1).
        const int kt = sB >> 6;
#pragma unroll
        for (int t = 0; t < 4; ++t) {
#pragma unroll
            for (int ns = 0; ns < 4; ++ns) {
                const int p  = ns & 1;
                const int h_ = wv * 2 + (ns >> 1);
                const int bh = b * 8 + h_;
                unsigned eu[4];
#pragma unroll
                for (int rr = 0; rr < 4; ++rr) eu[rr] = fbits(acc[t][ns][rr]) + 0x8000u;
                uint2 pk = make_uint2(__builtin_amdgcn_perm(eu[1], eu[0], PSEL),
                                      __builtin_amdgcn_perm(eu[3], eu[2], PSEL));
                size_t off = ((((size_t)bh * 16 + kt) * 4 + t) * 2 + p) * 256
                           + (quad * 16 + l15) * 4;
                *(uint2*)&vpF[off] = pk;
            }
        }
    }
}

// ---------------------------------------------------------------------------
// attn: LDS-FREE, BARRIER-FREE. block = 128 queries (4 waves x 32 q),
// 16 k-tiles of 64 keys. Mask pre-folded into K; no online max.
// K fragments: direct global loads (frag-packed, 1KB wave-contiguous),
// depth-2 register double-buffer (K(kt+1) loads while kt computes) -- the
// proj-r7 recipe. V fragments: direct global loads of frag-packed vpF
// (512B wave-contiguous), loaded for tile kt-1 at the start of tile kt.
// Cross-kt P pipeline as before. Zero barriers -> waves free-run and the
// MFMA and VALU/TRANS phases of different waves overlap (r7: MfmaUtil 50 +
// VALUBusy 46.5 with duration == SUM, i.e. no overlap at all).
// ---------------------------------------------------------------------------
__global__ __launch_bounds__(256) void attn_kernel(
    const short* __restrict__ qpH, const short* __restrict__ qpL,
    const short* __restrict__ kpH, const short* __restrict__ kpL,
    const short* __restrict__ vpF, float* __restrict__ out)
{
    const int tid  = threadIdx.x;
    const int lane = tid & 63;
    const int wv   = tid >> 6;
    const int l15  = lane & 15;
    const int quad = lane >> 4;

    // launch-linear id -> XCD-contiguous (bh, qt) assignment
    const int L  = (blockIdx.z * gridDim.y + blockIdx.y) * gridDim.x + blockIdx.x;
    const int li = L >> 3;
    const int bh = (L & 7) * 32 + (li >> 3);
    const int qt = li & 7;
    const int b  = bh >> 3;
    const int h  = bh & 7;
    const int woff = qt * 128 + wv * 32;

    bf8_t qh[2], ql[2];
#pragma unroll
    for (int qs = 0; qs < 2; ++qs) {
        const int grp = qt * 8 + wv * 2 + qs;      // (woff + qs*16) >> 4
        size_t off = (((size_t)bh * 64 + grp) * 64 + lane) * 8;
        qh[qs] = *(const bf8_t*)&qpH[off];
        ql[qs] = *(const bf8_t*)&qpL[off];
    }

    f4_t accO[2][2];
    f4_t accS[2];
#pragma unroll
    for (int i = 0; i < 2; ++i) {
        accS[i] = (f4_t){0.f, 0.f, 0.f, 0.f};
#pragma unroll
        for (int j = 0; j < 2; ++j) accO[i][j] = (f4_t){0.f, 0.f, 0.f, 0.f};
    }
    const bf4_t ones4 = {(short)0x3F80, (short)0x3F80, (short)0x3F80, (short)0x3F80};

    // walking base pointers (shorts); all in-tile offsets <= 4KB imm range
    const short* kHp = kpH + (size_t)bh * 64 * 512 + lane * 8;   // K tile kt
    const short* kLp = kpL + (size_t)bh * 64 * 512 + lane * 8;
    const short* vFp = vpF + (size_t)bh * 32768 + lane * 4;      // V tile (lags 1)

    bf8_t kAh[4], kAl[4], kBh[4], kBl[4];
    bf4_t vR[8];
    bf4_t pfA[2][4], pfB[2][4];

// one k-tile. KCUR*: K regs for tile KT; KNXT*: dest for K(KT+1) (from kHp/kLp,
// which point at tile KT+1). DO_PV: PV for tile KT-1 from vR (loaded here from
// vFp, pointing at tile KT-1) and PIN. POUT <- P(KT).
#define TILE(KCURh, KCURl, KNXTh, KNXTl, DO_KLOAD, DO_PV, PIN, POUT)            \
    {                                                                           \
        if (DO_KLOAD) {                                                         \
            _Pragma("unroll")                                                   \
            for (int ks = 0; ks < 4; ++ks) {                                    \
                KNXTh[ks] = *(const bf8_t*)&kHp[ks * 512];                      \
                KNXTl[ks] = *(const bf8_t*)&kLp[ks * 512];                      \
            }                                                                   \
        }                                                                       \
        if (DO_PV) {                                                            \
            _Pragma("unroll")                                                   \
            for (int ks = 0; ks < 4; ++ks) {                                    \
                vR[ks * 2]     = *(const bf4_t*)&vFp[(ks * 2) * 256];           \
                vR[ks * 2 + 1] = *(const bf4_t*)&vFp[(ks * 2 + 1) * 256];       \
            }                                                                   \
        }                                                                       \
        __builtin_amdgcn_s_setprio(1);                                          \
        _Pragma("unroll")                                                       \
        for (int ks = 0; ks < 4; ++ks) {                                        \
            f4_t sc[2];                                                         \
            _Pragma("unroll")                                                   \
            for (int qs = 0; qs < 2; ++qs) {                                    \
                f4_t c = __builtin_amdgcn_mfma_f32_16x16x32_bf16(KCURh[ks], qh[qs], \
                             (f4_t){0.f, 0.f, 0.f, 0.f}, 0, 0, 0);              \
                c = __builtin_amdgcn_mfma_f32_16x16x32_bf16(KCURl[ks], qh[qs], c, 0, 0, 0); \
                c = __builtin_amdgcn_mfma_f32_16x16x32_bf16(KCURh[ks], ql[qs], c, 0, 0, 0); \
                sc[qs] = c;                                                     \
            }                                                                   \
            if (DO_PV) {                                                        \
                _Pragma("unroll")                                               \
                for (int qs = 0; qs < 2; ++qs) {                                \
                    accO[qs][0] = __builtin_amdgcn_mfma_f32_16x16x16bf16_1k(    \
                                      vR[ks * 2], PIN[qs][ks], accO[qs][0], 0, 0, 0);     \
                    accO[qs][1] = __builtin_amdgcn_mfma_f32_16x16x16bf16_1k(    \
                                      vR[ks * 2 + 1], PIN[qs][ks], accO[qs][1], 0, 0, 0); \
                    accS[qs]    = __builtin_amdgcn_mfma_f32_16x16x16bf16_1k(    \
                                      ones4, PIN[qs][ks], accS[qs], 0, 0, 0);   \
                }                                                               \
            }                                                                   \
            _Pragma("unroll")                                                   \
            for (int qs = 0; qs < 2; ++qs) {                                    \
                unsigned eu[4];                                                 \
                _Pragma("unroll")                                               \
                for (int r = 0; r < 4; ++r)                                     \
                    eu[r] = fbits(EXP2F(sc[qs][r]));     /* truncate to bf16 */ \
                union { uint2 u; bf4_t v; } cv;                                 \
                cv.u = make_uint2(__builtin_amdgcn_perm(eu[1], eu[0], PSEL),    \
                                  __builtin_amdgcn_perm(eu[3], eu[2], PSEL));   \
                POUT[qs][ks] = cv.v;                                            \
            }                                                                   \
        }                                                                       \
        __builtin_amdgcn_s_setprio(0);                                          \
    }

    // ---- prologue: K(0) -> kA ----
#pragma unroll
    for (int ks = 0; ks < 4; ++ks) {
        kAh[ks] = *(const bf8_t*)&kHp[ks * 512];
        kAl[ks] = *(const bf8_t*)&kLp[ks * 512];
    }
    kHp += 2048; kLp += 2048;                          // -> K(1)

    TILE(kAh, kAl, kBh, kBl, 1, 0, pfA, pfA)           // tile 0: P(0)->pfA
    kHp += 2048; kLp += 2048;                          // -> K(2); vFp at V(0)

    for (int i = 0; i < 7; ++i) {
        TILE(kBh, kBl, kAh, kAl, 1, 1, pfA, pfB)       // odd tile 2i+1
        kHp += 2048; kLp += 2048; vFp += 2048;
        TILE(kAh, kAl, kBh, kBl, 1, 1, pfB, pfA)       // even tile 2i+2
        kHp += 2048; kLp += 2048; vFp += 2048;
    }
    TILE(kBh, kBl, kAh, kAl, 0, 1, pfA, pfB)           // tile 15 (no K load)
    vFp += 2048;                                       // -> V(15)

    // ---- drain: PV for tile 15 ----
#pragma unroll
    for (int ks = 0; ks < 4; ++ks) {
        vR[ks * 2]     = *(const bf4_t*)&vFp[(ks * 2) * 256];
        vR[ks * 2 + 1] = *(const bf4_t*)&vFp[(ks * 2 + 1) * 256];
    }
#pragma unroll
    for (int ks = 0; ks < 4; ++ks) {
#pragma unroll
        for (int qs = 0; qs < 2; ++qs) {
            accO[qs][0] = __builtin_amdgcn_mfma_f32_16x16x16bf16_1k(
                              vR[ks * 2], pfB[qs][ks], accO[qs][0], 0, 0, 0);
            accO[qs][1] = __builtin_amdgcn_mfma_f32_16x16x16bf16_1k(
                              vR[ks * 2 + 1], pfB[qs][ks], accO[qs][1], 0, 0, 0);
            accS[qs]    = __builtin_amdgcn_mfma_f32_16x16x16bf16_1k(
                              ones4, pfB[qs][ks], accS[qs], 0, 0, 0);
        }
    }
#undef TILE

    // ---- epilogue ----
#pragma unroll
    for (int qs = 0; qs < 2; ++qs) {
        float inv = 1.0f / accS[qs][0];
        int s = woff + qs * 16 + l15;
        float* op = out + ((size_t)b * 1024 + s) * 256 + h * 32;
#pragma unroll
        for (int dvs = 0; dvs < 2; ++dvs) {
            float4 o4 = make_float4(accO[qs][dvs][0] * inv, accO[qs][dvs][1] * inv,
                                    accO[qs][dvs][2] * inv, accO[qs][dvs][3] * inv);
            *(float4*)&op[dvs * 16 + quad * 4] = o4;
        }
    }
}

// ---------------------------------------------------------------------------
extern "C" void kernel_launch(void* const* d_in, const int* in_sizes, int n_in,
                              void* d_out, int out_size, void* d_ws, size_t ws_size,
                              hipStream_t stream)
{
    const float* query = (const float*)d_in[0];
    const float* key   = (const float*)d_in[1];
    const float* value = (const float*)d_in[2];
    const float* mask  = (const float*)d_in[3];
    const float* Wq    = (const float*)d_in[4];
    const float* Wk    = (const float*)d_in[5];
    const float* Wv    = (const float*)d_in[6];
    float* out = (float*)d_out;

    const size_t per = (size_t)B_ * H_ * S_ * DK_;
    short* qpH = (short*)d_ws;
    short* qpL = qpH + per;
    short* kpH = qpL + per;
    short* kpL = kpH + per;
    short* vpF = kpL + per;
    short* WpH = vpF + per;
    short* WpL = WpH + 3 * 256 * 256;

    prep_w<<<dim3(24, 4), 256, 0, stream>>>(Wq, Wk, Wv, WpH, WpL);
    proj_kernel<<<dim3(512, 3), 256, 0, stream>>>(query, key, value, mask, WpH, WpL,
                                                  qpH, qpL, kpH, kpL, vpF);
    attn_kernel<<<dim3(8, H_, B_), 256, 0, stream>>>(qpH, qpL, kpH, kpL, vpF, out);
}